// Round 1
// baseline (1705.532 us; speedup 1.0000x reference)
//
#include <hip/hip_runtime.h>
#include <cstdio>
#include <cstdint>

#define F_IN 128
#define D 256
#define EPS 1e-5f

// ---------------- edge sort (counting sort by dst) ----------------

__global__ void k_hist(const int* __restrict__ dst, int E, int* __restrict__ counts) {
    for (int e = blockIdx.x * blockDim.x + threadIdx.x; e < E; e += gridDim.x * blockDim.x)
        atomicAdd(&counts[dst[e]], 1);
}

// single-block exclusive scan over counts -> row_start[0..Nn], cursor copy
__global__ __launch_bounds__(1024) void k_scan(const int* __restrict__ counts,
                                               int* __restrict__ row_start,
                                               int* __restrict__ cursor,
                                               int Nn, int Etot) {
    __shared__ int wsum[16];
    __shared__ int s_carry;
    const int T = 1024;
    int lane = threadIdx.x & 63, wid = threadIdx.x >> 6;
    if (threadIdx.x == 0) s_carry = 0;
    __syncthreads();
    for (int base = 0; base < Nn; base += T) {
        int i = base + (int)threadIdx.x;
        int v = (i < Nn) ? counts[i] : 0;
        int x = v;
        #pragma unroll
        for (int off = 1; off < 64; off <<= 1) {
            int t = __shfl_up(x, off, 64);
            if (lane >= off) x += t;
        }
        if (lane == 63) wsum[wid] = x;
        __syncthreads();
        if (wid == 0 && lane < 16) {
            int w = wsum[lane];
            #pragma unroll
            for (int off = 1; off < 16; off <<= 1) {
                int t = __shfl_up(w, off, 64);
                if (lane >= off) w += t;
            }
            wsum[lane] = w;
        }
        __syncthreads();
        int wave_off = (wid == 0) ? 0 : wsum[wid - 1];
        int incl = x + wave_off;
        int carry = s_carry;
        if (i < Nn) {
            int ex = carry + incl - v;
            row_start[i] = ex;
            cursor[i] = ex;
        }
        __syncthreads();
        if (threadIdx.x == T - 1) s_carry = carry + incl;
        __syncthreads();
    }
    if (threadIdx.x == 0) row_start[Nn] = Etot;
}

__global__ void k_sort(const int* __restrict__ src, const int* __restrict__ dst,
                       const float* __restrict__ ew, int E,
                       int* __restrict__ cursor, int* __restrict__ s_src,
                       float* __restrict__ s_w) {
    for (int e = blockIdx.x * blockDim.x + threadIdx.x; e < E; e += gridDim.x * blockDim.x) {
        int d = dst[e];
        int pos = atomicAdd(&cursor[d], 1);
        s_src[pos] = src[e];
        s_w[pos] = ew[e];
    }
}

// ---------------- aggregation: one wave per dst node ----------------

__global__ __launch_bounds__(256) void k_agg(const float* __restrict__ h,
                                             const int* __restrict__ row_start,
                                             const int* __restrict__ s_src,
                                             const float* __restrict__ s_w,
                                             float* __restrict__ agg, int Nn) {
    int node = (int)((blockIdx.x * blockDim.x + threadIdx.x) >> 6);
    int lane = threadIdx.x & 63;
    if (node >= Nn) return;
    int beg = row_start[node], end = row_start[node + 1];
    const float4* hv = (const float4*)h;
    float4 acc = make_float4(0.f, 0.f, 0.f, 0.f);
    int e = beg;
    for (; e + 1 < end; e += 2) {
        int s0 = s_src[e], s1 = s_src[e + 1];
        float w0 = s_w[e], w1 = s_w[e + 1];
        float4 v0 = hv[(size_t)s0 * 64 + lane];
        float4 v1 = hv[(size_t)s1 * 64 + lane];
        acc.x += w0 * v0.x + w1 * v1.x;
        acc.y += w0 * v0.y + w1 * v1.y;
        acc.z += w0 * v0.z + w1 * v1.z;
        acc.w += w0 * v0.w + w1 * v1.w;
    }
    if (e < end) {
        int s0 = s_src[e];
        float w0 = s_w[e];
        float4 v0 = hv[(size_t)s0 * 64 + lane];
        acc.x += w0 * v0.x; acc.y += w0 * v0.y;
        acc.z += w0 * v0.z; acc.w += w0 * v0.w;
    }
    ((float4*)agg)[(size_t)node * 64 + lane] = acc;
}

// ---------------- fp32 GEMM: out = A1@W1 (+ A2@W2) + bias ----------------
// A row-major [M,K], W row-major [K,256], out [M,256]
#define GBM 128
#define GBN 128
#define GBK 16

__global__ __launch_bounds__(256) void gemm_bias(
    const float* __restrict__ A1, int K1, const float* __restrict__ W1,
    const float* __restrict__ A2, int K2, const float* __restrict__ W2,
    const float* __restrict__ bias, float* __restrict__ out, int M, int Ncols) {
    __shared__ float As[GBK][132];   // padded stride to break store conflicts
    __shared__ float Bs[GBK][GBN];
    int tid = threadIdx.x;
    int tx = tid & 15;   // col group
    int ty = tid >> 4;   // row group
    int row0 = blockIdx.x * GBM;
    int col0 = blockIdx.y * GBN;
    float acc[8][8];
    #pragma unroll
    for (int i = 0; i < 8; ++i)
        #pragma unroll
        for (int j = 0; j < 8; ++j) acc[i][j] = 0.f;

    for (int pass = 0; pass < 2; ++pass) {
        const float* A = pass ? A2 : A1;
        const float* W = pass ? W2 : W1;
        int K = pass ? K2 : K1;
        if (K == 0) continue;
        for (int k0 = 0; k0 < K; k0 += GBK) {
            #pragma unroll
            for (int i = 0; i < 2; ++i) {
                int e = tid + 256 * i;       // float4 index 0..511
                int m = e >> 2;              // 0..127
                int kq = (e & 3) * 4;        // 0,4,8,12
                int grow = row0 + m;
                float4 v = make_float4(0.f, 0.f, 0.f, 0.f);
                if (grow < M) v = *(const float4*)&A[(size_t)grow * K + k0 + kq];
                As[kq + 0][m] = v.x;
                As[kq + 1][m] = v.y;
                As[kq + 2][m] = v.z;
                As[kq + 3][m] = v.w;
            }
            #pragma unroll
            for (int i = 0; i < 2; ++i) {
                int e = tid + 256 * i;
                int kk = e >> 5;             // 0..15
                int c = (e & 31) * 4;        // 0..124
                *(float4*)&Bs[kk][c] = *(const float4*)&W[(size_t)(k0 + kk) * Ncols + col0 + c];
            }
            __syncthreads();
            #pragma unroll
            for (int kk = 0; kk < GBK; ++kk) {
                float a[8], b[8];
                *(float4*)&a[0] = *(const float4*)&As[kk][ty * 8];
                *(float4*)&a[4] = *(const float4*)&As[kk][ty * 8 + 4];
                *(float4*)&b[0] = *(const float4*)&Bs[kk][tx * 4];        // cols tx*4..+3
                *(float4*)&b[4] = *(const float4*)&Bs[kk][64 + tx * 4];   // cols 64+tx*4..+3
                #pragma unroll
                for (int i = 0; i < 8; ++i)
                    #pragma unroll
                    for (int j = 0; j < 8; ++j)
                        acc[i][j] = fmaf(a[i], b[j], acc[i][j]);
            }
            __syncthreads();
        }
    }
    int gc0 = col0 + tx * 4;
    int gc1 = col0 + 64 + tx * 4;
    float b0[4], b1[4];
    #pragma unroll
    for (int j = 0; j < 4; ++j) { b0[j] = bias[gc0 + j]; b1[j] = bias[gc1 + j]; }
    #pragma unroll
    for (int i = 0; i < 8; ++i) {
        int grow = row0 + ty * 8 + i;
        if (grow >= M) continue;
        float4 v0, v1;
        v0.x = acc[i][0] + b0[0]; v0.y = acc[i][1] + b0[1];
        v0.z = acc[i][2] + b0[2]; v0.w = acc[i][3] + b0[3];
        v1.x = acc[i][4] + b1[0]; v1.y = acc[i][5] + b1[1];
        v1.z = acc[i][6] + b1[2]; v1.w = acc[i][7] + b1[3];
        *(float4*)&out[(size_t)grow * Ncols + gc0] = v0;
        *(float4*)&out[(size_t)grow * Ncols + gc1] = v1;
    }
}

// ---------------- BN stats + apply ----------------

__global__ __launch_bounds__(256) void colstats(const float* __restrict__ h,
                                                float* __restrict__ stats, int Nrows) {
    int c = threadIdx.x;  // 256 columns
    float s = 0.f, s2 = 0.f;
    for (int r = blockIdx.x; r < Nrows; r += gridDim.x) {
        float v = h[(size_t)r * D + c];
        s += v; s2 += v * v;
    }
    atomicAdd(&stats[c], s);
    atomicAdd(&stats[D + c], s2);
}

__global__ __launch_bounds__(256) void bn_prelu(float* __restrict__ h,
                                                const float* __restrict__ stats,
                                                const float* __restrict__ g,
                                                const float* __restrict__ be,
                                                const float* __restrict__ a_ptr,
                                                int total4, int Nrows) {
    int idx = blockIdx.x * 256 + threadIdx.x;
    if (idx >= total4) return;
    float a = a_ptr[0];
    float inv = 1.0f / (float)Nrows;
    int c4 = (idx & 63) * 4;
    float4 v = ((const float4*)h)[idx];
    float vin[4] = {v.x, v.y, v.z, v.w};
    float o[4];
    #pragma unroll
    for (int t = 0; t < 4; ++t) {
        int c = c4 + t;
        float m = stats[c] * inv;
        float var = stats[D + c] * inv - m * m;
        float sc = rsqrtf(var + EPS) * g[c];
        float sh = be[c] - m * sc;
        float u = vin[t] * sc + sh;
        o[t] = u >= 0.f ? u : a * u;
    }
    ((float4*)h)[idx] = make_float4(o[0], o[1], o[2], o[3]);
}

// ---------------- final head ----------------

__global__ __launch_bounds__(256) void k_final(const float* __restrict__ x,
                                               const float* __restrict__ h,
                                               const float* __restrict__ Wf,
                                               const float* __restrict__ bf,
                                               float* __restrict__ z, int Nn) {
    int node = (int)((blockIdx.x * blockDim.x + threadIdx.x) >> 6);
    int lane = threadIdx.x & 63;
    if (node >= Nn) return;
    float s = 0.f;
    s += x[(size_t)node * F_IN + lane] * Wf[lane];
    s += x[(size_t)node * F_IN + 64 + lane] * Wf[64 + lane];
    #pragma unroll
    for (int i = 0; i < 4; ++i)
        s += h[(size_t)node * D + i * 64 + lane] * Wf[F_IN + i * 64 + lane];
    #pragma unroll
    for (int off = 32; off; off >>= 1) s += __shfl_down(s, off, 64);
    if (lane == 0) z[node] = s + bf[0];
}

__global__ __launch_bounds__(256) void k_zstats(const float* __restrict__ z,
                                                float* __restrict__ zs, int n) {
    float s = 0.f, s2 = 0.f;
    for (int i = blockIdx.x * blockDim.x + threadIdx.x; i < n; i += gridDim.x * blockDim.x) {
        float v = z[i];
        s += v; s2 += v * v;
    }
    #pragma unroll
    for (int off = 32; off; off >>= 1) {
        s += __shfl_down(s, off, 64);
        s2 += __shfl_down(s2, off, 64);
    }
    __shared__ float ws[4], ws2[4];
    int lane = threadIdx.x & 63, wid = threadIdx.x >> 6;
    if (lane == 0) { ws[wid] = s; ws2[wid] = s2; }
    __syncthreads();
    if (threadIdx.x == 0) {
        float a = ws[0] + ws[1] + ws[2] + ws[3];
        float b = ws2[0] + ws2[1] + ws2[2] + ws2[3];
        atomicAdd(&zs[0], a);
        atomicAdd(&zs[1], b);
    }
}

__global__ __launch_bounds__(256) void k_logsm(const float* __restrict__ z,
                                               const float* __restrict__ zs,
                                               const float* __restrict__ g,
                                               const float* __restrict__ be,
                                               const float* __restrict__ a_ptr,
                                               float* __restrict__ out, int C, int Ntot) {
    __shared__ float red[4], red2[4];
    int t = threadIdx.x;
    int lane = t & 63, wid = t >> 6;
    float mean = zs[0] / (float)Ntot;
    float var = zs[1] / (float)Ntot - mean * mean;
    float sc = rsqrtf(var + EPS) * g[0];
    float sh = be[0] - mean * sc;
    float a = a_ptr[0];
    const float* zg = z + (size_t)blockIdx.x * C;
    float vals[4];
    int cnt = 0;
    float mx = -3.4e38f;
    for (int i = t; i < C; i += 256) {
        float u = zg[i] * sc + sh;
        u = u >= 0.f ? u : a * u;
        vals[cnt++] = u;
        mx = fmaxf(mx, u);
    }
    #pragma unroll
    for (int off = 32; off; off >>= 1) mx = fmaxf(mx, __shfl_down(mx, off, 64));
    if (lane == 0) red[wid] = mx;
    __syncthreads();
    float M4 = fmaxf(fmaxf(red[0], red[1]), fmaxf(red[2], red[3]));
    float se = 0.f;
    for (int j = 0; j < cnt; ++j) se += expf(vals[j] - M4);
    #pragma unroll
    for (int off = 32; off; off >>= 1) se += __shfl_down(se, off, 64);
    if (lane == 0) red2[wid] = se;
    __syncthreads();
    float S4 = red2[0] + red2[1] + red2[2] + red2[3];
    float lse = logf(S4) + M4;
    cnt = 0;
    for (int i = t; i < C; i += 256) out[(size_t)blockIdx.x * C + i] = vals[cnt++] - lse;
}

// ---------------- launch ----------------

extern "C" void kernel_launch(void* const* d_in, const int* in_sizes, int n_in,
                              void* d_out, int out_size, void* d_ws, size_t ws_size,
                              hipStream_t stream) {
    const float* x      = (const float*)d_in[0];
    const int*   eidx   = (const int*)d_in[1];
    const float* e_w    = (const float*)d_in[2];
    const float* W_pre  = (const float*)d_in[4];
    const float* b_pre  = (const float*)d_in[5];
    const float* g_pre  = (const float*)d_in[6];
    const float* be_pre = (const float*)d_in[7];
    const float* a_pre  = (const float*)d_in[8];
    const float* W_rel  = (const float*)d_in[9];
    const float* b_rel  = (const float*)d_in[10];
    const float* W_root = (const float*)d_in[11];
    const float* g_conv = (const float*)d_in[12];
    const float* be_conv= (const float*)d_in[13];
    const float* a_conv = (const float*)d_in[14];
    const float* W_post = (const float*)d_in[15];
    const float* b_post = (const float*)d_in[16];
    const float* g_post = (const float*)d_in[17];
    const float* be_post= (const float*)d_in[18];
    const float* a_post = (const float*)d_in[19];
    const float* W_fin  = (const float*)d_in[20];
    const float* b_fin  = (const float*)d_in[21];
    const float* g_fin  = (const float*)d_in[22];
    const float* be_fin = (const float*)d_in[23];
    const float* a_fin  = (const float*)d_in[24];

    const int N = in_sizes[0] / F_IN;   // 50000
    const int E = in_sizes[2];          // 800000
    const int L = in_sizes[14];         // 3
    const int* e_src = eidx;
    const int* e_dst = eidx + E;

    // workspace carve-up
    uint8_t* w = (uint8_t*)d_ws;
    size_t used = 0;
    auto alloc = [&](size_t bytes) -> void* {
        void* p = w + used;
        used += (bytes + 255) & ~(size_t)255;
        return p;
    };
    float* h0       = (float*)alloc((size_t)N * D * 4);
    float* h1       = (float*)alloc((size_t)N * D * 4);
    float* agg      = (float*)alloc((size_t)N * D * 4);
    float* z        = (float*)alloc((size_t)N * 4);
    float* statsall = (float*)alloc((size_t)(5 * 2 * D + 2) * 4);
    int*   counts   = (int*)alloc((size_t)N * 4);
    int*   row_start= (int*)alloc((size_t)(N + 1) * 4);
    int*   cursor   = (int*)alloc((size_t)N * 4);
    int*   s_src    = (int*)alloc((size_t)E * 4);
    float* s_w      = (float*)alloc((size_t)E * 4);
    if (used > ws_size) {
        fprintf(stderr, "kernel_launch: ws too small (%zu > %zu)\n", used, ws_size);
        return;
    }
    float* st_pre  = statsall;
    float* st_post = statsall + 4 * 2 * D;
    float* zstats  = statsall + 5 * 2 * D;

    hipMemsetAsync(counts, 0, (size_t)N * 4, stream);
    hipMemsetAsync(statsall, 0, (size_t)(5 * 2 * D + 2) * 4, stream);

    // edge sort by dst
    k_hist<<<1024, 256, 0, stream>>>(e_dst, E, counts);
    k_scan<<<1, 1024, 0, stream>>>(counts, row_start, cursor, N, E);
    k_sort<<<1024, 256, 0, stream>>>(e_src, e_dst, e_w, E, cursor, s_src, s_w);

    dim3 gg((N + GBM - 1) / GBM, D / GBN);
    const int bn_blocks = (N * (D / 4) + 255) / 256;
    const int wave_blocks = (N + 3) / 4;

    // preprocess
    gemm_bias<<<gg, 256, 0, stream>>>(x, F_IN, W_pre, nullptr, 0, nullptr, b_pre, h0, N, D);
    colstats<<<256, 256, 0, stream>>>(h0, st_pre, N);
    bn_prelu<<<bn_blocks, 256, 0, stream>>>(h0, st_pre, g_pre, be_pre, a_pre, N * (D / 4), N);

    float* hc = h0;
    float* hn = h1;
    for (int l = 0; l < L; ++l) {
        float* st = statsall + (1 + l) * 2 * D;
        k_agg<<<wave_blocks, 256, 0, stream>>>(hc, row_start, s_src, s_w, agg, N);
        gemm_bias<<<gg, 256, 0, stream>>>(agg, D, W_rel + (size_t)l * D * D,
                                          hc, D, W_root + (size_t)l * D * D,
                                          b_rel + (size_t)l * D, hn, N, D);
        colstats<<<256, 256, 0, stream>>>(hn, st, N);
        bn_prelu<<<bn_blocks, 256, 0, stream>>>(hn, st, g_conv + (size_t)l * D,
                                                be_conv + (size_t)l * D, a_conv + l,
                                                N * (D / 4), N);
        float* tmp = hc; hc = hn; hn = tmp;
    }

    // postprocess
    gemm_bias<<<gg, 256, 0, stream>>>(hc, D, W_post, nullptr, 0, nullptr, b_post, hn, N, D);
    colstats<<<256, 256, 0, stream>>>(hn, st_post, N);
    bn_prelu<<<bn_blocks, 256, 0, stream>>>(hn, st_post, g_post, be_post, a_post, N * (D / 4), N);

    // head
    k_final<<<wave_blocks, 256, 0, stream>>>(x, hn, W_fin, b_fin, z, N);
    k_zstats<<<64, 256, 0, stream>>>(z, zstats, N);
    k_logsm<<<N / 1000, 256, 0, stream>>>(z, zstats, g_fin, be_fin, a_fin,
                                          (float*)d_out, 1000, N);
}

// Round 2
// 997.825 us; speedup vs baseline: 1.7092x; 1.7092x over previous
//
#include <hip/hip_runtime.h>
#include <cstdio>
#include <cstdint>

#define F_IN 128
#define D 256
#define EPS 1e-5f

typedef unsigned short bfu;
typedef __attribute__((ext_vector_type(8))) short bf16x8;
typedef __attribute__((ext_vector_type(4))) float f32x4;

__device__ __forceinline__ float bf2f(unsigned u) {
    return __uint_as_float(u << 16);
}
__device__ __forceinline__ bfu f2bf(float f) {
    unsigned u = __float_as_uint(f);
    return (bfu)((u + 0x7fffu + ((u >> 16) & 1u)) >> 16);
}

#define GLOBAL_LOAD_LDS16(gp, lp)                                                  \
    __builtin_amdgcn_global_load_lds((const __attribute__((address_space(1))) void*)(gp), \
                                     (__attribute__((address_space(3))) void*)(lp), 16, 0, 0)

// ---------------- edge sort (counting sort by dst) ----------------

__global__ void k_hist(const int* __restrict__ dst, int E, int* __restrict__ counts) {
    for (int e = blockIdx.x * blockDim.x + threadIdx.x; e < E; e += gridDim.x * blockDim.x)
        atomicAdd(&counts[dst[e]], 1);
}

__global__ __launch_bounds__(1024) void k_scan(const int* __restrict__ counts,
                                               int* __restrict__ row_start,
                                               int* __restrict__ cursor,
                                               int Nn, int Etot) {
    __shared__ int wsum[16];
    __shared__ int s_carry;
    const int T = 1024;
    int lane = threadIdx.x & 63, wid = threadIdx.x >> 6;
    if (threadIdx.x == 0) s_carry = 0;
    __syncthreads();
    for (int base = 0; base < Nn; base += T) {
        int i = base + (int)threadIdx.x;
        int v = (i < Nn) ? counts[i] : 0;
        int x = v;
        #pragma unroll
        for (int off = 1; off < 64; off <<= 1) {
            int t = __shfl_up(x, off, 64);
            if (lane >= off) x += t;
        }
        if (lane == 63) wsum[wid] = x;
        __syncthreads();
        if (wid == 0 && lane < 16) {
            int w = wsum[lane];
            #pragma unroll
            for (int off = 1; off < 16; off <<= 1) {
                int t = __shfl_up(w, off, 64);
                if (lane >= off) w += t;
            }
            wsum[lane] = w;
        }
        __syncthreads();
        int wave_off = (wid == 0) ? 0 : wsum[wid - 1];
        int incl = x + wave_off;
        int carry = s_carry;
        if (i < Nn) {
            int ex = carry + incl - v;
            row_start[i] = ex;
            cursor[i] = ex;
        }
        __syncthreads();
        if (threadIdx.x == T - 1) s_carry = carry + incl;
        __syncthreads();
    }
    if (threadIdx.x == 0) row_start[Nn] = Etot;
}

__global__ void k_sort(const int* __restrict__ src, const int* __restrict__ dst,
                       const float* __restrict__ ew, int E,
                       int* __restrict__ cursor, int* __restrict__ s_src,
                       float* __restrict__ s_w) {
    for (int e = blockIdx.x * blockDim.x + threadIdx.x; e < E; e += gridDim.x * blockDim.x) {
        int d = dst[e];
        int pos = atomicAdd(&cursor[d], 1);
        s_src[pos] = src[e];
        s_w[pos] = ew[e];
    }
}

// ---------------- conversions ----------------

// fp32 [rows,cols] -> bf16, processed as float4 -> 4 bf16 packed in uint2
__global__ __launch_bounds__(256) void k_cvt(const float* __restrict__ in,
                                             bfu* __restrict__ outb, int total4) {
    int idx = blockIdx.x * 256 + threadIdx.x;
    if (idx >= total4) return;
    float4 v = ((const float4*)in)[idx];
    uint2 o;
    o.x = (unsigned)f2bf(v.x) | ((unsigned)f2bf(v.y) << 16);
    o.y = (unsigned)f2bf(v.z) | ((unsigned)f2bf(v.w) << 16);
    ((uint2*)outb)[idx] = o;
}

// W [K,Ncol] fp32 -> Wt [Ncol,K] bf16
__global__ __launch_bounds__(256) void k_trans(const float* __restrict__ W,
                                               bfu* __restrict__ Wt, int K, int Ncol) {
    int idx = blockIdx.x * 256 + threadIdx.x;
    if (idx >= K * Ncol) return;
    int n = idx / K, k = idx % K;
    Wt[idx] = f2bf(W[(size_t)k * Ncol + n]);
}

// ---------------- aggregation (bf16 h) ----------------

__global__ __launch_bounds__(256) void k_agg(const bfu* __restrict__ h,
                                             const int* __restrict__ row_start,
                                             const int* __restrict__ s_src,
                                             const float* __restrict__ s_w,
                                             bfu* __restrict__ agg, int Nn) {
    int node = (int)((blockIdx.x * blockDim.x + threadIdx.x) >> 6);
    int lane = threadIdx.x & 63;
    if (node >= Nn) return;
    int beg = row_start[node], end = row_start[node + 1];
    const uint2* hv = (const uint2*)h;
    float a0 = 0.f, a1 = 0.f, a2 = 0.f, a3 = 0.f;
    int e = beg;
    for (; e + 1 < end; e += 2) {
        int s0 = s_src[e], s1 = s_src[e + 1];
        float w0 = s_w[e], w1 = s_w[e + 1];
        uint2 v0 = hv[(size_t)s0 * 64 + lane];
        uint2 v1 = hv[(size_t)s1 * 64 + lane];
        a0 += w0 * bf2f(v0.x & 0xffffu) + w1 * bf2f(v1.x & 0xffffu);
        a1 += w0 * bf2f(v0.x >> 16)     + w1 * bf2f(v1.x >> 16);
        a2 += w0 * bf2f(v0.y & 0xffffu) + w1 * bf2f(v1.y & 0xffffu);
        a3 += w0 * bf2f(v0.y >> 16)     + w1 * bf2f(v1.y >> 16);
    }
    if (e < end) {
        int s0 = s_src[e];
        float w0 = s_w[e];
        uint2 v0 = hv[(size_t)s0 * 64 + lane];
        a0 += w0 * bf2f(v0.x & 0xffffu);
        a1 += w0 * bf2f(v0.x >> 16);
        a2 += w0 * bf2f(v0.y & 0xffffu);
        a3 += w0 * bf2f(v0.y >> 16);
    }
    uint2 o;
    o.x = (unsigned)f2bf(a0) | ((unsigned)f2bf(a1) << 16);
    o.y = (unsigned)f2bf(a2) | ((unsigned)f2bf(a3) << 16);
    ((uint2*)agg)[(size_t)node * 64 + lane] = o;
}

// ---------------- bf16 MFMA GEMM ----------------
// out[M,256] = A1[M,K1]@W1t^T (+ A2[M,K2]@W2t^T) + bias.  Wt layouts are [256,K] bf16.
// A buffers must be padded to a multiple of 128 rows (reads OK, stores guarded).
#define BM 128
#define BN 128
#define BK 32

__global__ __launch_bounds__(256) void gemm_mfma(
    const bfu* __restrict__ A1, int K1, const bfu* __restrict__ W1t,
    const bfu* __restrict__ A2, int K2, const bfu* __restrict__ W2t,
    const float* __restrict__ bias, float* __restrict__ out, int M, int Ncols) {
    __shared__ bfu As[BM * BK];   // row-major [128][32], contiguous (global_load_lds)
    __shared__ bfu Bs[BN * BK];   // [128 n][32 k]
    int tid = threadIdx.x;
    int lane = tid & 63;
    int w = tid >> 6;            // wave 0..3
    int wm = (w >> 1) * 64;      // wave quadrant
    int wn = (w & 1) * 64;
    int row0 = blockIdx.x * BM;
    int col0 = blockIdx.y * BN;

    f32x4 acc[4][4];
    #pragma unroll
    for (int i = 0; i < 4; ++i)
        #pragma unroll
        for (int j = 0; j < 4; ++j) acc[i][j] = (f32x4)(0.f);

    int lr = lane >> 2;          // row within 16-row segment
    int lc = (lane & 3) * 8;     // element offset within row (8 bf16 = 16B)
    int rsel = lane & 15;        // fragment row/col select
    int kq = (lane >> 4) * 8;    // fragment k offset

    const int KT = K1 + K2;
    for (int k0 = 0; k0 < KT; k0 += BK) {
        const bfu* A; const bfu* Wt; int K; int kk;
        if (k0 < K1) { A = A1; Wt = W1t; K = K1; kk = k0; }
        else         { A = A2; Wt = W2t; K = K2; kk = k0 - K1; }
        __syncthreads();  // protect LDS from previous iteration's readers
        #pragma unroll
        for (int t = 0; t < 2; ++t) {
            int seg = w * 2 + t;                 // 0..7 : 16 rows each
            int r = seg * 16 + lr;
            const bfu* gp = A + (size_t)(row0 + r) * K + kk + lc;
            GLOBAL_LOAD_LDS16(gp, As + seg * 512);
        }
        #pragma unroll
        for (int t = 0; t < 2; ++t) {
            int seg = w * 2 + t;
            int n = seg * 16 + lr;
            const bfu* gp = Wt + (size_t)(col0 + n) * K + kk + lc;
            GLOBAL_LOAD_LDS16(gp, Bs + seg * 512);
        }
        __syncthreads();  // drains vmcnt(0): staged data visible

        bf16x8 af[4], bf[4];
        #pragma unroll
        for (int i = 0; i < 4; ++i)
            af[i] = *(const bf16x8*)&As[(wm + i * 16 + rsel) * BK + kq];
        #pragma unroll
        for (int j = 0; j < 4; ++j)
            bf[j] = *(const bf16x8*)&Bs[(wn + j * 16 + rsel) * BK + kq];
        #pragma unroll
        for (int i = 0; i < 4; ++i)
            #pragma unroll
            for (int j = 0; j < 4; ++j)
                acc[i][j] = __builtin_amdgcn_mfma_f32_16x16x32_bf16(af[i], bf[j], acc[i][j], 0, 0, 0);
    }

    // epilogue: C/D map col=lane&15, row=(lane>>4)*4+r
    #pragma unroll
    for (int j = 0; j < 4; ++j) {
        int col = col0 + wn + j * 16 + rsel;
        float bv = bias[col];
        #pragma unroll
        for (int i = 0; i < 4; ++i) {
            int rowb = row0 + wm + i * 16 + (lane >> 4) * 4;
            #pragma unroll
            for (int r = 0; r < 4; ++r) {
                int row = rowb + r;
                if (row < M) out[(size_t)row * Ncols + col] = acc[i][j][r] + bv;
            }
        }
    }
}

// ---------------- BN stats + apply ----------------

__global__ __launch_bounds__(256) void colstats(const float* __restrict__ h,
                                                float* __restrict__ stats, int Nrows) {
    int c = threadIdx.x;
    float s = 0.f, s2 = 0.f;
    for (int r = blockIdx.x; r < Nrows; r += gridDim.x) {
        float v = h[(size_t)r * D + c];
        s += v; s2 += v * v;
    }
    atomicAdd(&stats[c], s);
    atomicAdd(&stats[D + c], s2);
}

// read fp32 GEMM out, write bf16 h
__global__ __launch_bounds__(256) void bn_prelu_bf16(const float* __restrict__ hf,
                                                     const float* __restrict__ stats,
                                                     const float* __restrict__ g,
                                                     const float* __restrict__ be,
                                                     const float* __restrict__ a_ptr,
                                                     bfu* __restrict__ hb,
                                                     int total4, int Nrows) {
    int idx = blockIdx.x * 256 + threadIdx.x;
    if (idx >= total4) return;
    float a = a_ptr[0];
    float inv = 1.0f / (float)Nrows;
    int c4 = (idx & 63) * 4;
    float4 v = ((const float4*)hf)[idx];
    float vin[4] = {v.x, v.y, v.z, v.w};
    bfu o[4];
    #pragma unroll
    for (int t = 0; t < 4; ++t) {
        int c = c4 + t;
        float m = stats[c] * inv;
        float var = stats[D + c] * inv - m * m;
        float sc = rsqrtf(var + EPS) * g[c];
        float sh = be[c] - m * sc;
        float u = vin[t] * sc + sh;
        o[t] = f2bf(u >= 0.f ? u : a * u);
    }
    uint2 ov;
    ov.x = (unsigned)o[0] | ((unsigned)o[1] << 16);
    ov.y = (unsigned)o[2] | ((unsigned)o[3] << 16);
    ((uint2*)hb)[idx] = ov;
}

// ---------------- final head ----------------

__global__ __launch_bounds__(256) void k_final(const float* __restrict__ x,
                                               const bfu* __restrict__ h,
                                               const float* __restrict__ Wf,
                                               const float* __restrict__ bf_,
                                               float* __restrict__ z, int Nn) {
    int node = (int)((blockIdx.x * blockDim.x + threadIdx.x) >> 6);
    int lane = threadIdx.x & 63;
    if (node >= Nn) return;
    float s = 0.f;
    s += x[(size_t)node * F_IN + lane] * Wf[lane];
    s += x[(size_t)node * F_IN + 64 + lane] * Wf[64 + lane];
    float4 wv = ((const float4*)(Wf + F_IN))[lane];
    uint2 hv = ((const uint2*)h)[(size_t)node * 64 + lane];
    s += bf2f(hv.x & 0xffffu) * wv.x + bf2f(hv.x >> 16) * wv.y
       + bf2f(hv.y & 0xffffu) * wv.z + bf2f(hv.y >> 16) * wv.w;
    #pragma unroll
    for (int off = 32; off; off >>= 1) s += __shfl_down(s, off, 64);
    if (lane == 0) z[node] = s + bf_[0];
}

__global__ __launch_bounds__(256) void k_zstats(const float* __restrict__ z,
                                                float* __restrict__ zs, int n) {
    float s = 0.f, s2 = 0.f;
    for (int i = blockIdx.x * blockDim.x + threadIdx.x; i < n; i += gridDim.x * blockDim.x) {
        float v = z[i];
        s += v; s2 += v * v;
    }
    #pragma unroll
    for (int off = 32; off; off >>= 1) {
        s += __shfl_down(s, off, 64);
        s2 += __shfl_down(s2, off, 64);
    }
    __shared__ float ws[4], ws2[4];
    int lane = threadIdx.x & 63, wid = threadIdx.x >> 6;
    if (lane == 0) { ws[wid] = s; ws2[wid] = s2; }
    __syncthreads();
    if (threadIdx.x == 0) {
        atomicAdd(&zs[0], ws[0] + ws[1] + ws[2] + ws[3]);
        atomicAdd(&zs[1], ws2[0] + ws2[1] + ws2[2] + ws2[3]);
    }
}

__global__ __launch_bounds__(256) void k_logsm(const float* __restrict__ z,
                                               const float* __restrict__ zs,
                                               const float* __restrict__ g,
                                               const float* __restrict__ be,
                                               const float* __restrict__ a_ptr,
                                               float* __restrict__ out, int C, int Ntot) {
    __shared__ float red[4], red2[4];
    int t = threadIdx.x;
    int lane = t & 63, wid = t >> 6;
    float mean = zs[0] / (float)Ntot;
    float var = zs[1] / (float)Ntot - mean * mean;
    float sc = rsqrtf(var + EPS) * g[0];
    float sh = be[0] - mean * sc;
    float a = a_ptr[0];
    const float* zg = z + (size_t)blockIdx.x * C;
    float vals[4];
    int cnt = 0;
    float mx = -3.4e38f;
    for (int i = t; i < C; i += 256) {
        float u = zg[i] * sc + sh;
        u = u >= 0.f ? u : a * u;
        vals[cnt++] = u;
        mx = fmaxf(mx, u);
    }
    #pragma unroll
    for (int off = 32; off; off >>= 1) mx = fmaxf(mx, __shfl_down(mx, off, 64));
    if (lane == 0) red[wid] = mx;
    __syncthreads();
    float M4 = fmaxf(fmaxf(red[0], red[1]), fmaxf(red[2], red[3]));
    float se = 0.f;
    for (int j = 0; j < cnt; ++j) se += expf(vals[j] - M4);
    #pragma unroll
    for (int off = 32; off; off >>= 1) se += __shfl_down(se, off, 64);
    if (lane == 0) red2[wid] = se;
    __syncthreads();
    float S4 = red2[0] + red2[1] + red2[2] + red2[3];
    float lse = logf(S4) + M4;
    cnt = 0;
    for (int i = t; i < C; i += 256) out[(size_t)blockIdx.x * C + i] = vals[cnt++] - lse;
}

// ---------------- launch ----------------

extern "C" void kernel_launch(void* const* d_in, const int* in_sizes, int n_in,
                              void* d_out, int out_size, void* d_ws, size_t ws_size,
                              hipStream_t stream) {
    const float* x      = (const float*)d_in[0];
    const int*   eidx   = (const int*)d_in[1];
    const float* e_w    = (const float*)d_in[2];
    const float* W_pre  = (const float*)d_in[4];
    const float* b_pre  = (const float*)d_in[5];
    const float* g_pre  = (const float*)d_in[6];
    const float* be_pre = (const float*)d_in[7];
    const float* a_pre  = (const float*)d_in[8];
    const float* W_rel  = (const float*)d_in[9];
    const float* b_rel  = (const float*)d_in[10];
    const float* W_root = (const float*)d_in[11];
    const float* g_conv = (const float*)d_in[12];
    const float* be_conv= (const float*)d_in[13];
    const float* a_conv = (const float*)d_in[14];
    const float* W_post = (const float*)d_in[15];
    const float* b_post = (const float*)d_in[16];
    const float* g_post = (const float*)d_in[17];
    const float* be_post= (const float*)d_in[18];
    const float* a_post = (const float*)d_in[19];
    const float* W_fin  = (const float*)d_in[20];
    const float* b_fin  = (const float*)d_in[21];
    const float* g_fin  = (const float*)d_in[22];
    const float* be_fin = (const float*)d_in[23];
    const float* a_fin  = (const float*)d_in[24];

    const int N = in_sizes[0] / F_IN;   // 50000
    const int E = in_sizes[2];          // 800000
    const int L = in_sizes[14];         // 3
    const int Npad = ((N + BM - 1) / BM) * BM;
    const int* e_src = eidx;
    const int* e_dst = eidx + E;

    uint8_t* wsp = (uint8_t*)d_ws;
    size_t used = 0;
    auto alloc = [&](size_t bytes) -> void* {
        void* p = wsp + used;
        used += (bytes + 255) & ~(size_t)255;
        return p;
    };
    bfu*   xb       = (bfu*)alloc((size_t)Npad * F_IN * 2);
    bfu*   hb0      = (bfu*)alloc((size_t)Npad * D * 2);
    bfu*   hb1      = (bfu*)alloc((size_t)Npad * D * 2);
    bfu*   aggb     = (bfu*)alloc((size_t)Npad * D * 2);
    float* outf     = (float*)alloc((size_t)N * D * 4);
    bfu*   Wt_pre   = (bfu*)alloc((size_t)D * F_IN * 2);
    bfu*   Wt_rel   = (bfu*)alloc((size_t)L * D * D * 2);
    bfu*   Wt_root  = (bfu*)alloc((size_t)L * D * D * 2);
    bfu*   Wt_post  = (bfu*)alloc((size_t)D * D * 2);
    float* z        = (float*)alloc((size_t)N * 4);
    float* statsall = (float*)alloc((size_t)(5 * 2 * D + 2) * 4);
    int*   counts   = (int*)alloc((size_t)N * 4);
    int*   row_start= (int*)alloc((size_t)(N + 1) * 4);
    int*   cursor   = (int*)alloc((size_t)N * 4);
    int*   s_src    = (int*)alloc((size_t)E * 4);
    float* s_w      = (float*)alloc((size_t)E * 4);
    if (used > ws_size) {
        fprintf(stderr, "kernel_launch: ws too small (%zu > %zu)\n", used, ws_size);
        return;
    }
    float* st_pre  = statsall;
    float* st_post = statsall + 4 * 2 * D;
    float* zstats  = statsall + 5 * 2 * D;

    hipMemsetAsync(counts, 0, (size_t)N * 4, stream);
    hipMemsetAsync(statsall, 0, (size_t)(5 * 2 * D + 2) * 4, stream);

    // edge sort by dst
    k_hist<<<1024, 256, 0, stream>>>(e_dst, E, counts);
    k_scan<<<1, 1024, 0, stream>>>(counts, row_start, cursor, N, E);
    k_sort<<<1024, 256, 0, stream>>>(e_src, e_dst, e_w, E, cursor, s_src, s_w);

    // weight transposes + input convert (tiny)
    k_cvt<<<(N * (F_IN / 4) + 255) / 256, 256, 0, stream>>>(x, xb, N * (F_IN / 4));
    k_trans<<<(F_IN * D + 255) / 256, 256, 0, stream>>>(W_pre, Wt_pre, F_IN, D);
    for (int l = 0; l < L; ++l) {
        k_trans<<<(D * D + 255) / 256, 256, 0, stream>>>(W_rel + (size_t)l * D * D,
                                                         Wt_rel + (size_t)l * D * D, D, D);
        k_trans<<<(D * D + 255) / 256, 256, 0, stream>>>(W_root + (size_t)l * D * D,
                                                         Wt_root + (size_t)l * D * D, D, D);
    }
    k_trans<<<(D * D + 255) / 256, 256, 0, stream>>>(W_post, Wt_post, D, D);

    dim3 gg(Npad / BM, D / BN);
    const int bn_blocks = (N * (D / 4) + 255) / 256;
    const int wave_blocks = (N + 3) / 4;

    // preprocess
    gemm_mfma<<<gg, 256, 0, stream>>>(xb, F_IN, Wt_pre, nullptr, 0, nullptr, b_pre, outf, N, D);
    colstats<<<256, 256, 0, stream>>>(outf, st_pre, N);
    bn_prelu_bf16<<<bn_blocks, 256, 0, stream>>>(outf, st_pre, g_pre, be_pre, a_pre,
                                                 hb0, N * (D / 4), N);

    bfu* hc = hb0;
    bfu* hn = hb1;
    for (int l = 0; l < L; ++l) {
        float* st = statsall + (1 + l) * 2 * D;
        k_agg<<<wave_blocks, 256, 0, stream>>>(hc, row_start, s_src, s_w, aggb, N);
        gemm_mfma<<<gg, 256, 0, stream>>>(aggb, D, Wt_rel + (size_t)l * D * D,
                                          hc, D, Wt_root + (size_t)l * D * D,
                                          b_rel + (size_t)l * D, outf, N, D);
        colstats<<<256, 256, 0, stream>>>(outf, st, N);
        bn_prelu_bf16<<<bn_blocks, 256, 0, stream>>>(outf, st, g_conv + (size_t)l * D,
                                                     be_conv + (size_t)l * D, a_conv + l,
                                                     hn, N * (D / 4), N);
        bfu* tmp = hc; hc = hn; hn = tmp;
    }

    // postprocess
    gemm_mfma<<<gg, 256, 0, stream>>>(hc, D, Wt_post, nullptr, 0, nullptr, b_post, outf, N, D);
    colstats<<<256, 256, 0, stream>>>(outf, st_post, N);
    bn_prelu_bf16<<<bn_blocks, 256, 0, stream>>>(outf, st_post, g_post, be_post, a_post,
                                                 hn, N * (D / 4), N);

    // head
    k_final<<<wave_blocks, 256, 0, stream>>>(x, hn, W_fin, b_fin, z, N);
    k_zstats<<<64, 256, 0, stream>>>(z, zstats, N);
    k_logsm<<<N / 1000, 256, 0, stream>>>(z, zstats, g_fin, be_fin, a_fin,
                                          (float*)d_out, 1000, N);
}

// Round 3
// 765.825 us; speedup vs baseline: 2.2271x; 1.3029x over previous
//
#include <hip/hip_runtime.h>
#include <cstdio>
#include <cstdint>

#define F_IN 128
#define D 256
#define EPS 1e-5f

typedef unsigned short bfu;
typedef __attribute__((ext_vector_type(8))) short bf16x8;
typedef __attribute__((ext_vector_type(4))) float f32x4;

__device__ __forceinline__ float bf2f(unsigned u) {
    return __uint_as_float(u << 16);
}
__device__ __forceinline__ bfu f2bf(float f) {
    unsigned u = __float_as_uint(f);
    return (bfu)((u + 0x7fffu + ((u >> 16) & 1u)) >> 16);
}

#define GLOBAL_LOAD_LDS16(gp, lp)                                                  \
    __builtin_amdgcn_global_load_lds((const __attribute__((address_space(1))) void*)(gp), \
                                     (__attribute__((address_space(3))) void*)(lp), 16, 0, 0)

// ---------------- edge sort (counting sort by dst) ----------------

__global__ void k_hist(const int* __restrict__ dst, int E, int* __restrict__ counts) {
    for (int e = blockIdx.x * blockDim.x + threadIdx.x; e < E; e += gridDim.x * blockDim.x)
        atomicAdd(&counts[dst[e]], 1);
}

// block-local exclusive scan of 256 counts; writes block total
__global__ __launch_bounds__(256) void k_scan1(const int* __restrict__ counts,
                                               int* __restrict__ excl,
                                               int* __restrict__ btot, int Nn) {
    __shared__ int wsum[4];
    int i = blockIdx.x * 256 + threadIdx.x;
    int lane = threadIdx.x & 63, wid = threadIdx.x >> 6;
    int v = (i < Nn) ? counts[i] : 0;
    int x = v;
    #pragma unroll
    for (int off = 1; off < 64; off <<= 1) {
        int t = __shfl_up(x, off, 64);
        if (lane >= off) x += t;
    }
    if (lane == 63) wsum[wid] = x;
    __syncthreads();
    if (threadIdx.x == 0) {
        int run = 0;
        #pragma unroll
        for (int wv = 0; wv < 4; ++wv) { int t = wsum[wv]; wsum[wv] = run; run += t; }
        btot[blockIdx.x] = run;
    }
    __syncthreads();
    if (i < Nn) excl[i] = wsum[wid] + x - v;
}

// exclusive scan of block totals (nb <= 256), in place
__global__ __launch_bounds__(256) void k_scan2(int* __restrict__ btot, int nb) {
    __shared__ int wsum[4];
    int t = threadIdx.x;
    int lane = t & 63, wid = t >> 6;
    int v = (t < nb) ? btot[t] : 0;
    int x = v;
    #pragma unroll
    for (int off = 1; off < 64; off <<= 1) {
        int s = __shfl_up(x, off, 64);
        if (lane >= off) x += s;
    }
    if (lane == 63) wsum[wid] = x;
    __syncthreads();
    if (t == 0) {
        int run = 0;
        #pragma unroll
        for (int wv = 0; wv < 4; ++wv) { int s = wsum[wv]; wsum[wv] = run; run += s; }
    }
    __syncthreads();
    if (t < nb) btot[t] = wsum[wid] + x - v;
}

__global__ __launch_bounds__(256) void k_scan3(int* __restrict__ row_start,
                                               int* __restrict__ cursor,
                                               const int* __restrict__ btot,
                                               int Nn, int Etot) {
    int i = blockIdx.x * 256 + threadIdx.x;
    if (i < Nn) {
        int rs = row_start[i] + btot[blockIdx.x];
        row_start[i] = rs;
        cursor[i] = rs;
    }
    if (blockIdx.x == 0 && threadIdx.x == 0) row_start[Nn] = Etot;
}

__global__ void k_sort(const int* __restrict__ src, const int* __restrict__ dst,
                       const float* __restrict__ ew, int E,
                       int* __restrict__ cursor, uint2* __restrict__ s_edge) {
    for (int e = blockIdx.x * blockDim.x + threadIdx.x; e < E; e += gridDim.x * blockDim.x) {
        int d = dst[e];
        int pos = atomicAdd(&cursor[d], 1);
        uint2 p;
        p.x = (unsigned)src[e];
        p.y = __float_as_uint(ew[e]);
        s_edge[pos] = p;
    }
}

// ---------------- conversions ----------------

__global__ __launch_bounds__(256) void k_cvt(const float* __restrict__ in,
                                             bfu* __restrict__ outb, int total4) {
    int idx = blockIdx.x * 256 + threadIdx.x;
    if (idx >= total4) return;
    float4 v = ((const float4*)in)[idx];
    uint2 o;
    o.x = (unsigned)f2bf(v.x) | ((unsigned)f2bf(v.y) << 16);
    o.y = (unsigned)f2bf(v.z) | ((unsigned)f2bf(v.w) << 16);
    ((uint2*)outb)[idx] = o;
}

// W [K,Ncol] fp32 -> Wt [Ncol,K] bf16
__global__ __launch_bounds__(256) void k_trans(const float* __restrict__ W,
                                               bfu* __restrict__ Wt, int K, int Ncol) {
    int idx = blockIdx.x * 256 + threadIdx.x;
    if (idx >= K * Ncol) return;
    int n = idx / K, k = idx % K;
    Wt[idx] = f2bf(W[(size_t)k * Ncol + n]);
}

// ---------------- aggregation (bf16 h, packed edges) ----------------

__global__ __launch_bounds__(256) void k_agg(const bfu* __restrict__ h,
                                             const int* __restrict__ row_start,
                                             const uint2* __restrict__ s_edge,
                                             bfu* __restrict__ agg, int Nn) {
    int node = (int)((blockIdx.x * blockDim.x + threadIdx.x) >> 6);
    int lane = threadIdx.x & 63;
    if (node >= Nn) return;
    int beg = row_start[node], end = row_start[node + 1];
    const uint2* hv = (const uint2*)h;
    float a0 = 0.f, a1 = 0.f, a2 = 0.f, a3 = 0.f;
    int e = beg;
    for (; e + 3 < end; e += 4) {
        uint2 p0 = s_edge[e], p1 = s_edge[e + 1], p2 = s_edge[e + 2], p3 = s_edge[e + 3];
        uint2 v0 = hv[(size_t)p0.x * 64 + lane];
        uint2 v1 = hv[(size_t)p1.x * 64 + lane];
        uint2 v2 = hv[(size_t)p2.x * 64 + lane];
        uint2 v3 = hv[(size_t)p3.x * 64 + lane];
        float w0 = __uint_as_float(p0.y), w1 = __uint_as_float(p1.y);
        float w2 = __uint_as_float(p2.y), w3 = __uint_as_float(p3.y);
        a0 += w0 * bf2f(v0.x & 0xffffu) + w1 * bf2f(v1.x & 0xffffu)
            + w2 * bf2f(v2.x & 0xffffu) + w3 * bf2f(v3.x & 0xffffu);
        a1 += w0 * bf2f(v0.x >> 16) + w1 * bf2f(v1.x >> 16)
            + w2 * bf2f(v2.x >> 16) + w3 * bf2f(v3.x >> 16);
        a2 += w0 * bf2f(v0.y & 0xffffu) + w1 * bf2f(v1.y & 0xffffu)
            + w2 * bf2f(v2.y & 0xffffu) + w3 * bf2f(v3.y & 0xffffu);
        a3 += w0 * bf2f(v0.y >> 16) + w1 * bf2f(v1.y >> 16)
            + w2 * bf2f(v2.y >> 16) + w3 * bf2f(v3.y >> 16);
    }
    for (; e < end; ++e) {
        uint2 p0 = s_edge[e];
        float w0 = __uint_as_float(p0.y);
        uint2 v0 = hv[(size_t)p0.x * 64 + lane];
        a0 += w0 * bf2f(v0.x & 0xffffu);
        a1 += w0 * bf2f(v0.x >> 16);
        a2 += w0 * bf2f(v0.y & 0xffffu);
        a3 += w0 * bf2f(v0.y >> 16);
    }
    uint2 o;
    o.x = (unsigned)f2bf(a0) | ((unsigned)f2bf(a1) << 16);
    o.y = (unsigned)f2bf(a2) | ((unsigned)f2bf(a3) << 16);
    ((uint2*)agg)[(size_t)node * 64 + lane] = o;
}

// ---------------- bf16 MFMA GEMM with fused column stats ----------------
// out[M,256] = A1[M,K1]@W1t^T (+ A2[M,K2]@W2t^T) + bias; stats[c] += col sums,
// stats[D+c] += col sumsq (rows < M only).  Wt layouts are [256,K] bf16.
#define BM 128
#define BN 128
#define BK 32

__global__ __launch_bounds__(256) void gemm_mfma(
    const bfu* __restrict__ A1, int K1, const bfu* __restrict__ W1t,
    const bfu* __restrict__ A2, int K2, const bfu* __restrict__ W2t,
    const float* __restrict__ bias, float* __restrict__ out,
    float* __restrict__ stats, int M, int Ncols) {
    __shared__ bfu As[BM * BK];
    __shared__ bfu Bs[BN * BK];
    int tid = threadIdx.x;
    int lane = tid & 63;
    int w = tid >> 6;
    int wm = (w >> 1) * 64;
    int wn = (w & 1) * 64;
    // col-block fastest (gridDim.x = Ncols/BN) so A-tiles are L2-shared
    int row0 = blockIdx.y * BM;
    int col0 = blockIdx.x * BN;

    f32x4 acc[4][4];
    #pragma unroll
    for (int i = 0; i < 4; ++i)
        #pragma unroll
        for (int j = 0; j < 4; ++j) acc[i][j] = (f32x4)(0.f);

    int lr = lane >> 2;
    int lc = (lane & 3) * 8;
    int rsel = lane & 15;
    int kq = (lane >> 4) * 8;

    const int KT = K1 + K2;
    for (int k0 = 0; k0 < KT; k0 += BK) {
        const bfu* A; const bfu* Wt; int K; int kk;
        if (k0 < K1) { A = A1; Wt = W1t; K = K1; kk = k0; }
        else         { A = A2; Wt = W2t; K = K2; kk = k0 - K1; }
        __syncthreads();
        #pragma unroll
        for (int t = 0; t < 2; ++t) {
            int seg = w * 2 + t;
            int r = seg * 16 + lr;
            const bfu* gp = A + (size_t)(row0 + r) * K + kk + lc;
            GLOBAL_LOAD_LDS16(gp, As + seg * 512);
        }
        #pragma unroll
        for (int t = 0; t < 2; ++t) {
            int seg = w * 2 + t;
            int n = seg * 16 + lr;
            const bfu* gp = Wt + (size_t)(col0 + n) * K + kk + lc;
            GLOBAL_LOAD_LDS16(gp, Bs + seg * 512);
        }
        __syncthreads();

        bf16x8 af[4], bfr[4];
        #pragma unroll
        for (int i = 0; i < 4; ++i)
            af[i] = *(const bf16x8*)&As[(wm + i * 16 + rsel) * BK + kq];
        #pragma unroll
        for (int j = 0; j < 4; ++j)
            bfr[j] = *(const bf16x8*)&Bs[(wn + j * 16 + rsel) * BK + kq];
        #pragma unroll
        for (int i = 0; i < 4; ++i)
            #pragma unroll
            for (int j = 0; j < 4; ++j)
                acc[i][j] = __builtin_amdgcn_mfma_f32_16x16x32_bf16(af[i], bfr[j], acc[i][j], 0, 0, 0);
    }

    // epilogue: C/D map col=lane&15, row=(lane>>4)*4+r ; fused column stats
    #pragma unroll
    for (int j = 0; j < 4; ++j) {
        int col = col0 + wn + j * 16 + rsel;
        float bv = bias[col];
        float s = 0.f, s2 = 0.f;
        #pragma unroll
        for (int i = 0; i < 4; ++i) {
            int rowb = row0 + wm + i * 16 + (lane >> 4) * 4;
            #pragma unroll
            for (int r = 0; r < 4; ++r) {
                int row = rowb + r;
                if (row < M) {
                    float v = acc[i][j][r] + bv;
                    out[(size_t)row * Ncols + col] = v;
                    s += v; s2 += v * v;
                }
            }
        }
        s  += __shfl_xor(s, 16, 64);  s  += __shfl_xor(s, 32, 64);
        s2 += __shfl_xor(s2, 16, 64); s2 += __shfl_xor(s2, 32, 64);
        if ((lane >> 4) == 0) {
            atomicAdd(&stats[col], s);
            atomicAdd(&stats[D + col], s2);
        }
    }
}

// ---------------- BN apply (pre + conv layers) ----------------

__global__ __launch_bounds__(256) void bn_prelu_bf16(const float* __restrict__ hf,
                                                     const float* __restrict__ stats,
                                                     const float* __restrict__ g,
                                                     const float* __restrict__ be,
                                                     const float* __restrict__ a_ptr,
                                                     bfu* __restrict__ hb,
                                                     int total4, int Nrows) {
    int idx = blockIdx.x * 256 + threadIdx.x;
    if (idx >= total4) return;
    float a = a_ptr[0];
    float inv = 1.0f / (float)Nrows;
    int c4 = (idx & 63) * 4;
    float4 v = ((const float4*)hf)[idx];
    float vin[4] = {v.x, v.y, v.z, v.w};
    bfu o[4];
    #pragma unroll
    for (int t = 0; t < 4; ++t) {
        int c = c4 + t;
        float m = stats[c] * inv;
        float var = stats[D + c] * inv - m * m;
        float sc = rsqrtf(var + EPS) * g[c];
        float sh = be[c] - m * sc;
        float u = vin[t] * sc + sh;
        o[t] = f2bf(u >= 0.f ? u : a * u);
    }
    uint2 ov;
    ov.x = (unsigned)o[0] | ((unsigned)o[1] << 16);
    ov.y = (unsigned)o[2] | ((unsigned)o[3] << 16);
    ((uint2*)hb)[idx] = ov;
}

// ---------------- fused post-BN + PReLU + head dot ----------------
// z[node] = prelu(bn(outf[node,:])) . Wf[128:384] + x[node,:] . Wf[0:128] + bf

__global__ __launch_bounds__(256) void k_final_fused(
    const float* __restrict__ x, const float* __restrict__ outf,
    const float* __restrict__ stats, const float* __restrict__ g,
    const float* __restrict__ be, const float* __restrict__ a_ptr,
    const float* __restrict__ Wf, const float* __restrict__ bf_,
    float* __restrict__ z, int Nn, int Nrows) {
    int node = (int)((blockIdx.x * blockDim.x + threadIdx.x) >> 6);
    int lane = threadIdx.x & 63;
    if (node >= Nn) return;
    float a = a_ptr[0];
    float inv = 1.0f / (float)Nrows;
    float s = x[(size_t)node * F_IN + lane] * Wf[lane]
            + x[(size_t)node * F_IN + 64 + lane] * Wf[64 + lane];
    float4 v  = ((const float4*)(outf + (size_t)node * D))[lane];
    float4 wv = ((const float4*)(Wf + F_IN))[lane];
    float4 st1 = ((const float4*)stats)[lane];
    float4 st2 = ((const float4*)(stats + D))[lane];
    float4 gv = ((const float4*)g)[lane];
    float4 bev = ((const float4*)be)[lane];
    float vin[4] = {v.x, v.y, v.z, v.w};
    float m1[4] = {st1.x, st1.y, st1.z, st1.w};
    float m2[4] = {st2.x, st2.y, st2.z, st2.w};
    float gg[4] = {gv.x, gv.y, gv.z, gv.w};
    float bb[4] = {bev.x, bev.y, bev.z, bev.w};
    float ww[4] = {wv.x, wv.y, wv.z, wv.w};
    #pragma unroll
    for (int t = 0; t < 4; ++t) {
        float m = m1[t] * inv;
        float var = m2[t] * inv - m * m;
        float sc = rsqrtf(var + EPS) * gg[t];
        float sh = bb[t] - m * sc;
        float u = vin[t] * sc + sh;
        u = u >= 0.f ? u : a * u;
        s += u * ww[t];
    }
    #pragma unroll
    for (int off = 32; off; off >>= 1) s += __shfl_down(s, off, 64);
    if (lane == 0) z[node] = s + bf_[0];
}

__global__ __launch_bounds__(256) void k_zstats(const float* __restrict__ z,
                                                float* __restrict__ zs, int n) {
    float s = 0.f, s2 = 0.f;
    for (int i = blockIdx.x * blockDim.x + threadIdx.x; i < n; i += gridDim.x * blockDim.x) {
        float v = z[i];
        s += v; s2 += v * v;
    }
    #pragma unroll
    for (int off = 32; off; off >>= 1) {
        s += __shfl_down(s, off, 64);
        s2 += __shfl_down(s2, off, 64);
    }
    __shared__ float ws[4], ws2[4];
    int lane = threadIdx.x & 63, wid = threadIdx.x >> 6;
    if (lane == 0) { ws[wid] = s; ws2[wid] = s2; }
    __syncthreads();
    if (threadIdx.x == 0) {
        atomicAdd(&zs[0], ws[0] + ws[1] + ws[2] + ws[3]);
        atomicAdd(&zs[1], ws2[0] + ws2[1] + ws2[2] + ws2[3]);
    }
}

__global__ __launch_bounds__(256) void k_logsm(const float* __restrict__ z,
                                               const float* __restrict__ zs,
                                               const float* __restrict__ g,
                                               const float* __restrict__ be,
                                               const float* __restrict__ a_ptr,
                                               float* __restrict__ out, int C, int Ntot) {
    __shared__ float red[4], red2[4];
    int t = threadIdx.x;
    int lane = t & 63, wid = t >> 6;
    float mean = zs[0] / (float)Ntot;
    float var = zs[1] / (float)Ntot - mean * mean;
    float sc = rsqrtf(var + EPS) * g[0];
    float sh = be[0] - mean * sc;
    float a = a_ptr[0];
    const float* zg = z + (size_t)blockIdx.x * C;
    float vals[4];
    int cnt = 0;
    float mx = -3.4e38f;
    for (int i = t; i < C; i += 256) {
        float u = zg[i] * sc + sh;
        u = u >= 0.f ? u : a * u;
        vals[cnt++] = u;
        mx = fmaxf(mx, u);
    }
    #pragma unroll
    for (int off = 32; off; off >>= 1) mx = fmaxf(mx, __shfl_down(mx, off, 64));
    if (lane == 0) red[wid] = mx;
    __syncthreads();
    float M4 = fmaxf(fmaxf(red[0], red[1]), fmaxf(red[2], red[3]));
    float se = 0.f;
    for (int j = 0; j < cnt; ++j) se += expf(vals[j] - M4);
    #pragma unroll
    for (int off = 32; off; off >>= 1) se += __shfl_down(se, off, 64);
    if (lane == 0) red2[wid] = se;
    __syncthreads();
    float S4 = red2[0] + red2[1] + red2[2] + red2[3];
    float lse = logf(S4) + M4;
    cnt = 0;
    for (int i = t; i < C; i += 256) out[(size_t)blockIdx.x * C + i] = vals[cnt++] - lse;
}

// ---------------- launch ----------------

extern "C" void kernel_launch(void* const* d_in, const int* in_sizes, int n_in,
                              void* d_out, int out_size, void* d_ws, size_t ws_size,
                              hipStream_t stream) {
    const float* x      = (const float*)d_in[0];
    const int*   eidx   = (const int*)d_in[1];
    const float* e_w    = (const float*)d_in[2];
    const float* W_pre  = (const float*)d_in[4];
    const float* b_pre  = (const float*)d_in[5];
    const float* g_pre  = (const float*)d_in[6];
    const float* be_pre = (const float*)d_in[7];
    const float* a_pre  = (const float*)d_in[8];
    const float* W_rel  = (const float*)d_in[9];
    const float* b_rel  = (const float*)d_in[10];
    const float* W_root = (const float*)d_in[11];
    const float* g_conv = (const float*)d_in[12];
    const float* be_conv= (const float*)d_in[13];
    const float* a_conv = (const float*)d_in[14];
    const float* W_post = (const float*)d_in[15];
    const float* b_post = (const float*)d_in[16];
    const float* g_post = (const float*)d_in[17];
    const float* be_post= (const float*)d_in[18];
    const float* a_post = (const float*)d_in[19];
    const float* W_fin  = (const float*)d_in[20];
    const float* b_fin  = (const float*)d_in[21];
    const float* g_fin  = (const float*)d_in[22];
    const float* be_fin = (const float*)d_in[23];
    const float* a_fin  = (const float*)d_in[24];

    const int N = in_sizes[0] / F_IN;   // 50000
    const int E = in_sizes[2];          // 800000
    const int L = in_sizes[14];         // 3
    const int Npad = ((N + BM - 1) / BM) * BM;
    const int SB = (N + 255) / 256;     // scan blocks
    const int* e_src = eidx;
    const int* e_dst = eidx + E;

    uint8_t* wsp = (uint8_t*)d_ws;
    size_t used = 0;
    auto alloc = [&](size_t bytes) -> void* {
        void* p = wsp + used;
        used += (bytes + 255) & ~(size_t)255;
        return p;
    };
    bfu*   xb       = (bfu*)alloc((size_t)Npad * F_IN * 2);
    bfu*   hb0      = (bfu*)alloc((size_t)Npad * D * 2);
    bfu*   hb1      = (bfu*)alloc((size_t)Npad * D * 2);
    bfu*   aggb     = (bfu*)alloc((size_t)Npad * D * 2);
    float* outf     = (float*)alloc((size_t)N * D * 4);
    bfu*   Wt_pre   = (bfu*)alloc((size_t)D * F_IN * 2);
    bfu*   Wt_rel   = (bfu*)alloc((size_t)L * D * D * 2);
    bfu*   Wt_root  = (bfu*)alloc((size_t)L * D * D * 2);
    bfu*   Wt_post  = (bfu*)alloc((size_t)D * D * 2);
    float* z        = (float*)alloc((size_t)N * 4);
    float* statsall = (float*)alloc((size_t)(5 * 2 * D + 2) * 4);
    int*   counts   = (int*)alloc((size_t)N * 4);
    int*   row_start= (int*)alloc((size_t)(N + 1) * 4);
    int*   cursor   = (int*)alloc((size_t)N * 4);
    int*   btot     = (int*)alloc((size_t)SB * 4);
    uint2* s_edge   = (uint2*)alloc((size_t)E * 8);
    if (used > ws_size) {
        fprintf(stderr, "kernel_launch: ws too small (%zu > %zu)\n", used, ws_size);
        return;
    }
    float* st_pre  = statsall;
    float* st_post = statsall + 4 * 2 * D;
    float* zstats  = statsall + 5 * 2 * D;

    hipMemsetAsync(counts, 0, (size_t)N * 4, stream);
    hipMemsetAsync(statsall, 0, (size_t)(5 * 2 * D + 2) * 4, stream);
    // zero pad rows so padded A-tiles contribute nothing surprising
    const int padrows = Npad - N;
    if (padrows > 0) {
        hipMemsetAsync(xb + (size_t)N * F_IN, 0, (size_t)padrows * F_IN * 2, stream);
        hipMemsetAsync(hb0 + (size_t)N * D, 0, (size_t)padrows * D * 2, stream);
        hipMemsetAsync(hb1 + (size_t)N * D, 0, (size_t)padrows * D * 2, stream);
        hipMemsetAsync(aggb + (size_t)N * D, 0, (size_t)padrows * D * 2, stream);
    }

    // edge sort by dst (counting sort, parallel scan)
    k_hist<<<1024, 256, 0, stream>>>(e_dst, E, counts);
    k_scan1<<<SB, 256, 0, stream>>>(counts, row_start, btot, N);
    k_scan2<<<1, 256, 0, stream>>>(btot, SB);
    k_scan3<<<SB, 256, 0, stream>>>(row_start, cursor, btot, N, E);
    k_sort<<<1024, 256, 0, stream>>>(e_src, e_dst, e_w, E, cursor, s_edge);

    // weight transposes + input convert (tiny)
    k_cvt<<<(N * (F_IN / 4) + 255) / 256, 256, 0, stream>>>(x, xb, N * (F_IN / 4));
    k_trans<<<(F_IN * D + 255) / 256, 256, 0, stream>>>(W_pre, Wt_pre, F_IN, D);
    for (int l = 0; l < L; ++l) {
        k_trans<<<(D * D + 255) / 256, 256, 0, stream>>>(W_rel + (size_t)l * D * D,
                                                         Wt_rel + (size_t)l * D * D, D, D);
        k_trans<<<(D * D + 255) / 256, 256, 0, stream>>>(W_root + (size_t)l * D * D,
                                                         Wt_root + (size_t)l * D * D, D, D);
    }
    k_trans<<<(D * D + 255) / 256, 256, 0, stream>>>(W_post, Wt_post, D, D);

    dim3 gg(D / BN, Npad / BM);   // col-block fastest for A-tile L2 reuse
    const int bn_blocks = (N * (D / 4) + 255) / 256;
    const int wave_blocks = (N + 3) / 4;

    // preprocess
    gemm_mfma<<<gg, 256, 0, stream>>>(xb, F_IN, Wt_pre, nullptr, 0, nullptr,
                                      b_pre, outf, st_pre, N, D);
    bn_prelu_bf16<<<bn_blocks, 256, 0, stream>>>(outf, st_pre, g_pre, be_pre, a_pre,
                                                 hb0, N * (D / 4), N);

    bfu* hc = hb0;
    bfu* hn = hb1;
    for (int l = 0; l < L; ++l) {
        float* st = statsall + (1 + l) * 2 * D;
        k_agg<<<wave_blocks, 256, 0, stream>>>(hc, row_start, s_edge, aggb, N);
        gemm_mfma<<<gg, 256, 0, stream>>>(aggb, D, Wt_rel + (size_t)l * D * D,
                                          hc, D, Wt_root + (size_t)l * D * D,
                                          b_rel + (size_t)l * D, outf, st, N, D);
        bn_prelu_bf16<<<bn_blocks, 256, 0, stream>>>(outf, st, g_conv + (size_t)l * D,
                                                     be_conv + (size_t)l * D, a_conv + l,
                                                     hn, N * (D / 4), N);
        bfu* tmp = hc; hc = hn; hn = tmp;
    }

    // postprocess gemm (stats fused) -> fused BN+PReLU+head dot
    gemm_mfma<<<gg, 256, 0, stream>>>(hc, D, Wt_post, nullptr, 0, nullptr,
                                      b_post, outf, st_post, N, D);
    k_final_fused<<<wave_blocks, 256, 0, stream>>>(x, outf, st_post, g_post, be_post,
                                                   a_post, W_fin, b_fin, z, N, N);
    k_zstats<<<64, 256, 0, stream>>>(z, zstats, N);
    k_logsm<<<N / 1000, 256, 0, stream>>>(z, zstats, g_fin, be_fin, a_fin,
                                          (float*)d_out, 1000, N);
}

// Round 4
// 671.796 us; speedup vs baseline: 2.5388x; 1.1400x over previous
//
#include <hip/hip_runtime.h>
#include <cstdio>
#include <cstdint>

#define F_IN 128
#define D 256
#define EPS 1e-5f

typedef unsigned short bfu;
typedef __attribute__((ext_vector_type(8))) short bf16x8;
typedef __attribute__((ext_vector_type(4))) float f32x4;

__device__ __forceinline__ float bf2f(unsigned u) {
    return __uint_as_float(u << 16);
}
__device__ __forceinline__ bfu f2bf(float f) {
    unsigned u = __float_as_uint(f);
    return (bfu)((u + 0x7fffu + ((u >> 16) & 1u)) >> 16);
}

#define GLOBAL_LOAD_LDS16(gp, lp)                                                  \
    __builtin_amdgcn_global_load_lds((const __attribute__((address_space(1))) void*)(gp), \
                                     (__attribute__((address_space(3))) void*)(lp), 16, 0, 0)

// ---------------- edge sort (counting sort by dst) ----------------

__global__ void k_hist(const int* __restrict__ dst, int E, int* __restrict__ counts) {
    for (int e = blockIdx.x * blockDim.x + threadIdx.x; e < E; e += gridDim.x * blockDim.x)
        atomicAdd(&counts[dst[e]], 1);
}

__global__ __launch_bounds__(256) void k_scan1(const int* __restrict__ counts,
                                               int* __restrict__ excl,
                                               int* __restrict__ btot, int Nn) {
    __shared__ int wsum[4];
    int i = blockIdx.x * 256 + threadIdx.x;
    int lane = threadIdx.x & 63, wid = threadIdx.x >> 6;
    int v = (i < Nn) ? counts[i] : 0;
    int x = v;
    #pragma unroll
    for (int off = 1; off < 64; off <<= 1) {
        int t = __shfl_up(x, off, 64);
        if (lane >= off) x += t;
    }
    if (lane == 63) wsum[wid] = x;
    __syncthreads();
    if (threadIdx.x == 0) {
        int run = 0;
        #pragma unroll
        for (int wv = 0; wv < 4; ++wv) { int t = wsum[wv]; wsum[wv] = run; run += t; }
        btot[blockIdx.x] = run;
    }
    __syncthreads();
    if (i < Nn) excl[i] = wsum[wid] + x - v;
}

__global__ __launch_bounds__(256) void k_scan2(int* __restrict__ btot, int nb) {
    __shared__ int wsum[4];
    int t = threadIdx.x;
    int lane = t & 63, wid = t >> 6;
    int v = (t < nb) ? btot[t] : 0;
    int x = v;
    #pragma unroll
    for (int off = 1; off < 64; off <<= 1) {
        int s = __shfl_up(x, off, 64);
        if (lane >= off) x += s;
    }
    if (lane == 63) wsum[wid] = x;
    __syncthreads();
    if (t == 0) {
        int run = 0;
        #pragma unroll
        for (int wv = 0; wv < 4; ++wv) { int s = wsum[wv]; wsum[wv] = run; run += s; }
    }
    __syncthreads();
    if (t < nb) btot[t] = wsum[wid] + x - v;
}

__global__ __launch_bounds__(256) void k_scan3(int* __restrict__ row_start,
                                               int* __restrict__ cursor,
                                               const int* __restrict__ btot,
                                               int Nn, int Etot) {
    int i = blockIdx.x * 256 + threadIdx.x;
    if (i < Nn) {
        int rs = row_start[i] + btot[blockIdx.x];
        row_start[i] = rs;
        cursor[i] = rs;
    }
    if (blockIdx.x == 0 && threadIdx.x == 0) row_start[Nn] = Etot;
}

__global__ void k_sort(const int* __restrict__ src, const int* __restrict__ dst,
                       const float* __restrict__ ew, int E,
                       int* __restrict__ cursor, uint2* __restrict__ s_edge) {
    for (int e = blockIdx.x * blockDim.x + threadIdx.x; e < E; e += gridDim.x * blockDim.x) {
        int d = dst[e];
        int pos = atomicAdd(&cursor[d], 1);
        uint2 p;
        p.x = (unsigned)src[e];
        p.y = __float_as_uint(ew[e]);
        s_edge[pos] = p;
    }
}

// ---------------- conversions ----------------

__global__ __launch_bounds__(256) void k_cvt(const float* __restrict__ in,
                                             bfu* __restrict__ outb, int total4) {
    int idx = blockIdx.x * 256 + threadIdx.x;
    if (idx >= total4) return;
    float4 v = ((const float4*)in)[idx];
    uint2 o;
    o.x = (unsigned)f2bf(v.x) | ((unsigned)f2bf(v.y) << 16);
    o.y = (unsigned)f2bf(v.z) | ((unsigned)f2bf(v.w) << 16);
    ((uint2*)outb)[idx] = o;
}

// all weight transposes in one launch: W[K,256] fp32 -> Wt[256,K] bf16
__global__ __launch_bounds__(256) void k_trans_all(
    const float* __restrict__ Wp, const float* __restrict__ Wr,
    const float* __restrict__ Wo, const float* __restrict__ Ws,
    bfu* __restrict__ Tp, bfu* __restrict__ Tr,
    bfu* __restrict__ To, bfu* __restrict__ Ts) {
    int region = blockIdx.y;
    const float* S; bfu* Dst; int K;
    if (region == 0)      { S = Wp;                      Dst = Tp;                      K = F_IN; }
    else if (region <= 3) { S = Wr + (region - 1) * D * D; Dst = Tr + (region - 1) * D * D; K = D; }
    else if (region <= 6) { S = Wo + (region - 4) * D * D; Dst = To + (region - 4) * D * D; K = D; }
    else                  { S = Ws;                      Dst = Ts;                      K = D; }
    int idx = blockIdx.x * 256 + threadIdx.x;
    if (idx >= K * D) return;
    int n = idx / K, k = idx % K;
    Dst[idx] = f2bf(S[(size_t)k * D + n]);
}

// ---------------- aggregation (bf16 h, packed edges) ----------------

__global__ __launch_bounds__(256) void k_agg(const bfu* __restrict__ h,
                                             const int* __restrict__ row_start,
                                             const uint2* __restrict__ s_edge,
                                             bfu* __restrict__ agg, int Nn) {
    int node = (int)((blockIdx.x * blockDim.x + threadIdx.x) >> 6);
    int lane = threadIdx.x & 63;
    if (node >= Nn) return;
    int beg = row_start[node], end = row_start[node + 1];
    const uint2* hv = (const uint2*)h;
    float a0 = 0.f, a1 = 0.f, a2 = 0.f, a3 = 0.f;
    int e = beg;
    for (; e + 3 < end; e += 4) {
        uint2 p0 = s_edge[e], p1 = s_edge[e + 1], p2 = s_edge[e + 2], p3 = s_edge[e + 3];
        uint2 v0 = hv[(size_t)p0.x * 64 + lane];
        uint2 v1 = hv[(size_t)p1.x * 64 + lane];
        uint2 v2 = hv[(size_t)p2.x * 64 + lane];
        uint2 v3 = hv[(size_t)p3.x * 64 + lane];
        float w0 = __uint_as_float(p0.y), w1 = __uint_as_float(p1.y);
        float w2 = __uint_as_float(p2.y), w3 = __uint_as_float(p3.y);
        a0 += w0 * bf2f(v0.x & 0xffffu) + w1 * bf2f(v1.x & 0xffffu)
            + w2 * bf2f(v2.x & 0xffffu) + w3 * bf2f(v3.x & 0xffffu);
        a1 += w0 * bf2f(v0.x >> 16) + w1 * bf2f(v1.x >> 16)
            + w2 * bf2f(v2.x >> 16) + w3 * bf2f(v3.x >> 16);
        a2 += w0 * bf2f(v0.y & 0xffffu) + w1 * bf2f(v1.y & 0xffffu)
            + w2 * bf2f(v2.y & 0xffffu) + w3 * bf2f(v3.y & 0xffffu);
        a3 += w0 * bf2f(v0.y >> 16) + w1 * bf2f(v1.y >> 16)
            + w2 * bf2f(v2.y >> 16) + w3 * bf2f(v3.y >> 16);
    }
    for (; e < end; ++e) {
        uint2 p0 = s_edge[e];
        float w0 = __uint_as_float(p0.y);
        uint2 v0 = hv[(size_t)p0.x * 64 + lane];
        a0 += w0 * bf2f(v0.x & 0xffffu);
        a1 += w0 * bf2f(v0.x >> 16);
        a2 += w0 * bf2f(v0.y & 0xffffu);
        a3 += w0 * bf2f(v0.y >> 16);
    }
    uint2 o;
    o.x = (unsigned)f2bf(a0) | ((unsigned)f2bf(a1) << 16);
    o.y = (unsigned)f2bf(a2) | ((unsigned)f2bf(a3) << 16);
    ((uint2*)agg)[(size_t)node * 64 + lane] = o;
}

// ---------------- bf16 MFMA GEMM (64x64 tile) with fused column stats ----------------
// out[M,256](bf16) = A1[M,K1]@W1t^T (+ A2[M,K2]@W2t^T) + bias; stats += col sums/sumsq.
// LDS k-group XOR swizzle: row r, k-group g lives at slot (g + (r>>1)) & 3.
#define BM 64
#define BN 64
#define BK 32

__global__ __launch_bounds__(256) void gemm_mfma(
    const bfu* __restrict__ A1, int K1, const bfu* __restrict__ W1t,
    const bfu* __restrict__ A2, int K2, const bfu* __restrict__ W2t,
    const float* __restrict__ bias, bfu* __restrict__ out,
    float* __restrict__ stats, int M, int Ncols) {
    __shared__ bfu lds[64 * 72];        // staging (As 2048 + Bs 2048) / epilogue Ct 64x72
    __shared__ float sstat[128];
    bfu* As = lds;
    bfu* Bs = lds + 2048;
    bfu* Ct = lds;
    int tid = threadIdx.x;
    int lane = tid & 63;
    int w = tid >> 6;
    int wm = (w >> 1) * 32;
    int wn = (w & 1) * 32;
    int row0 = blockIdx.y * BM;         // col-block fastest (gridDim.x = 4) for A L2 reuse
    int col0 = blockIdx.x * BN;

    if (tid < 128) sstat[tid] = 0.f;

    f32x4 acc[2][2];
    #pragma unroll
    for (int i = 0; i < 2; ++i)
        #pragma unroll
        for (int j = 0; j < 2; ++j) acc[i][j] = (f32x4)(0.f);

    // staging lane mapping: row r = w*16 + (lane>>2); slot gs = lane&3 holds k-group
    // g = (gs - (r>>1)) & 3
    int sr = w * 16 + (lane >> 2);
    int sg = ((lane & 3) - (sr >> 1)) & 3;
    size_t soff = (size_t)sr;           // row within tile
    int scol = sg * 8;                  // element offset of the fetched k-group

    int rsel = lane & 15;
    int kg = lane >> 4;                 // fragment k-group 0..3

    const int KT = K1 + K2;
    for (int k0 = 0; k0 < KT; k0 += BK) {
        const bfu* A; const bfu* Wt; int K; int kk;
        if (k0 < K1) { A = A1; Wt = W1t; K = K1; kk = k0; }
        else         { A = A2; Wt = W2t; K = K2; kk = k0 - K1; }
        __syncthreads();
        GLOBAL_LOAD_LDS16(A  + ((size_t)(row0) + soff) * K + kk + scol, As + w * 512);
        GLOBAL_LOAD_LDS16(Wt + ((size_t)(col0) + soff) * K + kk + scol, Bs + w * 512);
        __syncthreads();

        bf16x8 af[2], bfr[2];
        #pragma unroll
        for (int i = 0; i < 2; ++i) {
            int rr = wm + i * 16 + rsel;
            int gs = (kg + (rr >> 1)) & 3;
            af[i] = *(const bf16x8*)&As[rr * 32 + gs * 8];
        }
        #pragma unroll
        for (int j = 0; j < 2; ++j) {
            int nn = wn + j * 16 + rsel;
            int gs = (kg + (nn >> 1)) & 3;
            bfr[j] = *(const bf16x8*)&Bs[nn * 32 + gs * 8];
        }
        #pragma unroll
        for (int i = 0; i < 2; ++i)
            #pragma unroll
            for (int j = 0; j < 2; ++j)
                acc[i][j] = __builtin_amdgcn_mfma_f32_16x16x32_bf16(af[i], bfr[j], acc[i][j], 0, 0, 0);
    }

    __syncthreads();   // done reading staging LDS; reuse as Ct

    // stats + bf16 tile to LDS.  C/D map: col=lane&15, row=(lane>>4)*4+r
    int lgrp = lane >> 4;
    #pragma unroll
    for (int j = 0; j < 2; ++j) {
        int ccol = wn + j * 16 + rsel;
        float bv = bias[col0 + ccol];
        float s = 0.f, s2 = 0.f;
        #pragma unroll
        for (int i = 0; i < 2; ++i) {
            int rrb = wm + i * 16 + lgrp * 4;
            #pragma unroll
            for (int r = 0; r < 4; ++r) {
                int rr = rrb + r;
                float v = acc[i][j][r] + bv;
                Ct[rr * 72 + ccol] = f2bf(v);
                if (row0 + rr < M) { s += v; s2 += v * v; }
            }
        }
        s  += __shfl_xor(s, 16, 64);  s  += __shfl_xor(s, 32, 64);
        s2 += __shfl_xor(s2, 16, 64); s2 += __shfl_xor(s2, 32, 64);
        if (lgrp == 0) {
            atomicAdd(&sstat[ccol], s);
            atomicAdd(&sstat[64 + ccol], s2);
        }
    }
    __syncthreads();

    if (tid < 128) {
        int c = tid & 63;
        float v = sstat[tid];
        if (tid < 64) atomicAdd(&stats[col0 + c], v);
        else          atomicAdd(&stats[D + col0 + c], v);
    }

    // coalesced store: 4 threads per row, 32 B each
    int r = tid >> 2, cq = (tid & 3) * 16;
    if (row0 + r < M) {
        uint4 a = *(const uint4*)&Ct[r * 72 + cq];
        uint4 b = *(const uint4*)&Ct[r * 72 + cq + 8];
        uint4* gp = (uint4*)&out[(size_t)(row0 + r) * Ncols + col0 + cq];
        gp[0] = a;
        gp[1] = b;
    }
}

// ---------------- BN apply (pre + conv layers), bf16 in/out ----------------

__global__ __launch_bounds__(256) void bn_prelu_bf16(const bfu* __restrict__ hf,
                                                     const float* __restrict__ stats,
                                                     const float* __restrict__ g,
                                                     const float* __restrict__ be,
                                                     const float* __restrict__ a_ptr,
                                                     bfu* __restrict__ hb,
                                                     int total4, int Nrows) {
    int idx = blockIdx.x * 256 + threadIdx.x;
    if (idx >= total4) return;
    float a = a_ptr[0];
    float inv = 1.0f / (float)Nrows;
    int c4 = (idx & 63) * 4;
    uint2 v = ((const uint2*)hf)[idx];
    float vin[4] = {bf2f(v.x & 0xffffu), bf2f(v.x >> 16),
                    bf2f(v.y & 0xffffu), bf2f(v.y >> 16)};
    bfu o[4];
    #pragma unroll
    for (int t = 0; t < 4; ++t) {
        int c = c4 + t;
        float m = stats[c] * inv;
        float var = stats[D + c] * inv - m * m;
        float sc = rsqrtf(var + EPS) * g[c];
        float sh = be[c] - m * sc;
        float u = vin[t] * sc + sh;
        o[t] = f2bf(u >= 0.f ? u : a * u);
    }
    uint2 ov;
    ov.x = (unsigned)o[0] | ((unsigned)o[1] << 16);
    ov.y = (unsigned)o[2] | ((unsigned)o[3] << 16);
    ((uint2*)hb)[idx] = ov;
}

// ---------------- fused post-BN + PReLU + head dot ----------------

__global__ __launch_bounds__(256) void k_final_fused(
    const float* __restrict__ x, const bfu* __restrict__ outf,
    const float* __restrict__ stats, const float* __restrict__ g,
    const float* __restrict__ be, const float* __restrict__ a_ptr,
    const float* __restrict__ Wf, const float* __restrict__ bf_,
    float* __restrict__ z, int Nn, int Nrows) {
    int node = (int)((blockIdx.x * blockDim.x + threadIdx.x) >> 6);
    int lane = threadIdx.x & 63;
    if (node >= Nn) return;
    float a = a_ptr[0];
    float inv = 1.0f / (float)Nrows;
    float s = x[(size_t)node * F_IN + lane] * Wf[lane]
            + x[(size_t)node * F_IN + 64 + lane] * Wf[64 + lane];
    uint2 v  = ((const uint2*)outf)[(size_t)node * 64 + lane];
    float4 wv = ((const float4*)(Wf + F_IN))[lane];
    float4 st1 = ((const float4*)stats)[lane];
    float4 st2 = ((const float4*)(stats + D))[lane];
    float4 gv = ((const float4*)g)[lane];
    float4 bev = ((const float4*)be)[lane];
    float vin[4] = {bf2f(v.x & 0xffffu), bf2f(v.x >> 16),
                    bf2f(v.y & 0xffffu), bf2f(v.y >> 16)};
    float m1[4] = {st1.x, st1.y, st1.z, st1.w};
    float m2[4] = {st2.x, st2.y, st2.z, st2.w};
    float gg[4] = {gv.x, gv.y, gv.z, gv.w};
    float bb[4] = {bev.x, bev.y, bev.z, bev.w};
    float ww[4] = {wv.x, wv.y, wv.z, wv.w};
    #pragma unroll
    for (int t = 0; t < 4; ++t) {
        float m = m1[t] * inv;
        float var = m2[t] * inv - m * m;
        float sc = rsqrtf(var + EPS) * gg[t];
        float sh = bb[t] - m * sc;
        float u = vin[t] * sc + sh;
        u = u >= 0.f ? u : a * u;
        s += u * ww[t];
    }
    #pragma unroll
    for (int off = 32; off; off >>= 1) s += __shfl_down(s, off, 64);
    if (lane == 0) z[node] = s + bf_[0];
}

__global__ __launch_bounds__(256) void k_zstats(const float* __restrict__ z,
                                                float* __restrict__ zs, int n) {
    float s = 0.f, s2 = 0.f;
    for (int i = blockIdx.x * blockDim.x + threadIdx.x; i < n; i += gridDim.x * blockDim.x) {
        float v = z[i];
        s += v; s2 += v * v;
    }
    #pragma unroll
    for (int off = 32; off; off >>= 1) {
        s += __shfl_down(s, off, 64);
        s2 += __shfl_down(s2, off, 64);
    }
    __shared__ float ws[4], ws2[4];
    int lane = threadIdx.x & 63, wid = threadIdx.x >> 6;
    if (lane == 0) { ws[wid] = s; ws2[wid] = s2; }
    __syncthreads();
    if (threadIdx.x == 0) {
        atomicAdd(&zs[0], ws[0] + ws[1] + ws[2] + ws[3]);
        atomicAdd(&zs[1], ws2[0] + ws2[1] + ws2[2] + ws2[3]);
    }
}

__global__ __launch_bounds__(256) void k_logsm(const float* __restrict__ z,
                                               const float* __restrict__ zs,
                                               const float* __restrict__ g,
                                               const float* __restrict__ be,
                                               const float* __restrict__ a_ptr,
                                               float* __restrict__ out, int C, int Ntot) {
    __shared__ float red[4], red2[4];
    int t = threadIdx.x;
    int lane = t & 63, wid = t >> 6;
    float mean = zs[0] / (float)Ntot;
    float var = zs[1] / (float)Ntot - mean * mean;
    float sc = rsqrtf(var + EPS) * g[0];
    float sh = be[0] - mean * sc;
    float a = a_ptr[0];
    const float* zg = z + (size_t)blockIdx.x * C;
    float vals[4];
    int cnt = 0;
    float mx = -3.4e38f;
    for (int i = t; i < C; i += 256) {
        float u = zg[i] * sc + sh;
        u = u >= 0.f ? u : a * u;
        vals[cnt++] = u;
        mx = fmaxf(mx, u);
    }
    #pragma unroll
    for (int off = 32; off; off >>= 1) mx = fmaxf(mx, __shfl_down(mx, off, 64));
    if (lane == 0) red[wid] = mx;
    __syncthreads();
    float M4 = fmaxf(fmaxf(red[0], red[1]), fmaxf(red[2], red[3]));
    float se = 0.f;
    for (int j = 0; j < cnt; ++j) se += expf(vals[j] - M4);
    #pragma unroll
    for (int off = 32; off; off >>= 1) se += __shfl_down(se, off, 64);
    if (lane == 0) red2[wid] = se;
    __syncthreads();
    float S4 = red2[0] + red2[1] + red2[2] + red2[3];
    float lse = logf(S4) + M4;
    cnt = 0;
    for (int i = t; i < C; i += 256) out[(size_t)blockIdx.x * C + i] = vals[cnt++] - lse;
}

// ---------------- launch ----------------

extern "C" void kernel_launch(void* const* d_in, const int* in_sizes, int n_in,
                              void* d_out, int out_size, void* d_ws, size_t ws_size,
                              hipStream_t stream) {
    const float* x      = (const float*)d_in[0];
    const int*   eidx   = (const int*)d_in[1];
    const float* e_w    = (const float*)d_in[2];
    const float* W_pre  = (const float*)d_in[4];
    const float* b_pre  = (const float*)d_in[5];
    const float* g_pre  = (const float*)d_in[6];
    const float* be_pre = (const float*)d_in[7];
    const float* a_pre  = (const float*)d_in[8];
    const float* W_rel  = (const float*)d_in[9];
    const float* b_rel  = (const float*)d_in[10];
    const float* W_root = (const float*)d_in[11];
    const float* g_conv = (const float*)d_in[12];
    const float* be_conv= (const float*)d_in[13];
    const float* a_conv = (const float*)d_in[14];
    const float* W_post = (const float*)d_in[15];
    const float* b_post = (const float*)d_in[16];
    const float* g_post = (const float*)d_in[17];
    const float* be_post= (const float*)d_in[18];
    const float* a_post = (const float*)d_in[19];
    const float* W_fin  = (const float*)d_in[20];
    const float* b_fin  = (const float*)d_in[21];
    const float* g_fin  = (const float*)d_in[22];
    const float* be_fin = (const float*)d_in[23];
    const float* a_fin  = (const float*)d_in[24];

    const int N = in_sizes[0] / F_IN;   // 50000
    const int E = in_sizes[2];          // 800000
    const int L = in_sizes[14];         // 3
    const int Npad = ((N + BM - 1) / BM) * BM;
    const int SB = (N + 255) / 256;
    const int* e_src = eidx;
    const int* e_dst = eidx + E;

    uint8_t* wsp = (uint8_t*)d_ws;
    size_t used = 0;
    auto alloc = [&](size_t bytes) -> void* {
        void* p = wsp + used;
        used += (bytes + 255) & ~(size_t)255;
        return p;
    };
    bfu*   xb       = (bfu*)alloc((size_t)Npad * F_IN * 2);
    bfu*   hb0      = (bfu*)alloc((size_t)Npad * D * 2);
    bfu*   hb1      = (bfu*)alloc((size_t)Npad * D * 2);
    bfu*   aggb     = (bfu*)alloc((size_t)Npad * D * 2);
    bfu*   outb     = (bfu*)alloc((size_t)N * D * 2);
    bfu*   Wt_pre   = (bfu*)alloc((size_t)D * F_IN * 2);
    bfu*   Wt_rel   = (bfu*)alloc((size_t)L * D * D * 2);
    bfu*   Wt_root  = (bfu*)alloc((size_t)L * D * D * 2);
    bfu*   Wt_post  = (bfu*)alloc((size_t)D * D * 2);
    float* z        = (float*)alloc((size_t)N * 4);
    float* statsall = (float*)alloc((size_t)(5 * 2 * D + 2) * 4);
    int*   counts   = (int*)alloc((size_t)N * 4);
    int*   row_start= (int*)alloc((size_t)(N + 1) * 4);
    int*   cursor   = (int*)alloc((size_t)N * 4);
    int*   btot     = (int*)alloc((size_t)SB * 4);
    uint2* s_edge   = (uint2*)alloc((size_t)E * 8);
    if (used > ws_size) {
        fprintf(stderr, "kernel_launch: ws too small (%zu > %zu)\n", used, ws_size);
        return;
    }
    float* st_pre  = statsall;
    float* st_post = statsall + 4 * 2 * D;
    float* zstats  = statsall + 5 * 2 * D;

    hipMemsetAsync(counts, 0, (size_t)N * 4, stream);
    hipMemsetAsync(statsall, 0, (size_t)(5 * 2 * D + 2) * 4, stream);

    // edge sort by dst
    k_hist<<<1024, 256, 0, stream>>>(e_dst, E, counts);
    k_scan1<<<SB, 256, 0, stream>>>(counts, row_start, btot, N);
    k_scan2<<<1, 256, 0, stream>>>(btot, SB);
    k_scan3<<<SB, 256, 0, stream>>>(row_start, cursor, btot, N, E);
    k_sort<<<1024, 256, 0, stream>>>(e_src, e_dst, e_w, E, cursor, s_edge);

    // input convert + all weight transposes
    k_cvt<<<(N * (F_IN / 4) + 255) / 256, 256, 0, stream>>>(x, xb, N * (F_IN / 4));
    k_trans_all<<<dim3(256, 8), 256, 0, stream>>>(W_pre, W_rel, W_root, W_post,
                                                  Wt_pre, Wt_rel, Wt_root, Wt_post);

    dim3 gg(D / BN, Npad / BM);   // col-block fastest for A-tile L2 reuse
    const int bn_blocks = (N * (D / 4) + 255) / 256;
    const int wave_blocks = (N + 3) / 4;

    // preprocess
    gemm_mfma<<<gg, 256, 0, stream>>>(xb, F_IN, Wt_pre, nullptr, 0, nullptr,
                                      b_pre, outb, st_pre, N, D);
    bn_prelu_bf16<<<bn_blocks, 256, 0, stream>>>(outb, st_pre, g_pre, be_pre, a_pre,
                                                 hb0, N * (D / 4), N);

    bfu* hc = hb0;
    bfu* hn = hb1;
    for (int l = 0; l < L; ++l) {
        float* st = statsall + (1 + l) * 2 * D;
        k_agg<<<wave_blocks, 256, 0, stream>>>(hc, row_start, s_edge, aggb, N);
        gemm_mfma<<<gg, 256, 0, stream>>>(aggb, D, Wt_rel + (size_t)l * D * D,
                                          hc, D, Wt_root + (size_t)l * D * D,
                                          b_rel + (size_t)l * D, outb, st, N, D);
        bn_prelu_bf16<<<bn_blocks, 256, 0, stream>>>(outb, st, g_conv + (size_t)l * D,
                                                     be_conv + (size_t)l * D, a_conv + l,
                                                     hn, N * (D / 4), N);
        bfu* tmp = hc; hc = hn; hn = tmp;
    }

    // postprocess gemm (stats fused) -> fused BN+PReLU+head dot
    gemm_mfma<<<gg, 256, 0, stream>>>(hc, D, Wt_post, nullptr, 0, nullptr,
                                      b_post, outb, st_post, N, D);
    k_final_fused<<<wave_blocks, 256, 0, stream>>>(x, outb, st_post, g_post, be_post,
                                                   a_post, W_fin, b_fin, z, N, N);
    k_zstats<<<64, 256, 0, stream>>>(z, zstats, N);
    k_logsm<<<N / 1000, 256, 0, stream>>>(z, zstats, g_fin, be_fin, a_fin,
                                          (float*)d_out, 1000, N);
}

// Round 5
// 608.867 us; speedup vs baseline: 2.8012x; 1.1034x over previous
//
#include <hip/hip_runtime.h>
#include <cstdio>
#include <cstdint>

#define F_IN 128
#define D 256
#define EPS 1e-5f
// N must be < 65536 for the 16-bit src/dst packing in the edge sort (N=50000).

typedef unsigned short bfu;
typedef __attribute__((ext_vector_type(8))) short bf16x8;
typedef __attribute__((ext_vector_type(4))) float f32x4;

__device__ __forceinline__ float bf2f(unsigned u) {
    return __uint_as_float(u << 16);
}
__device__ __forceinline__ bfu f2bf(float f) {
    unsigned u = __float_as_uint(f);
    return (bfu)((u + 0x7fffu + ((u >> 16) & 1u)) >> 16);
}

#define GLOBAL_LOAD_LDS16(gp, lp)                                                  \
    __builtin_amdgcn_global_load_lds((const __attribute__((address_space(1))) void*)(gp), \
                                     (__attribute__((address_space(3))) void*)(lp), 16, 0, 0)

// ---------------- front end: cvt + weight transposes + bucket histogram ----------------
// region A: x fp32 -> bf16           (cvt_blocks blocks)
// region B: 8 weight transposes      (2048 blocks)
// region C: bucket histogram of dst  (512 blocks, LDS-aggregated)

__global__ __launch_bounds__(256) void k_front(
    const float* __restrict__ x, const int* __restrict__ e_dst,
    const float* __restrict__ Wp, const float* __restrict__ Wr,
    const float* __restrict__ Wo, const float* __restrict__ Ws,
    bfu* __restrict__ xb, bfu* __restrict__ Tp, bfu* __restrict__ Tr,
    bfu* __restrict__ To, bfu* __restrict__ Ts,
    int* __restrict__ bh, int cvt_blocks, int E, int nb, int total4) {
    int b = blockIdx.x;
    int tid = threadIdx.x;
    if (b < cvt_blocks) {
        int idx = b * 256 + tid;
        if (idx >= total4) return;
        float4 v = ((const float4*)x)[idx];
        uint2 o;
        o.x = (unsigned)f2bf(v.x) | ((unsigned)f2bf(v.y) << 16);
        o.y = (unsigned)f2bf(v.z) | ((unsigned)f2bf(v.w) << 16);
        ((uint2*)xb)[idx] = o;
    } else if (b < cvt_blocks + 2048) {
        int tb = b - cvt_blocks;
        int region = tb >> 8;
        const float* S; bfu* Dst; int K;
        if (region == 0)      { S = Wp;                        Dst = Tp;                        K = F_IN; }
        else if (region <= 3) { S = Wr + (region - 1) * D * D; Dst = Tr + (region - 1) * D * D; K = D; }
        else if (region <= 6) { S = Wo + (region - 4) * D * D; Dst = To + (region - 4) * D * D; K = D; }
        else                  { S = Ws;                        Dst = Ts;                        K = D; }
        int idx = (tb & 255) * 256 + tid;
        if (idx >= K * D) return;
        int n = idx / K, k = idx % K;
        Dst[idx] = f2bf(S[(size_t)k * D + n]);
    } else {
        __shared__ int lhist[256];
        int bb = b - cvt_blocks - 2048;
        lhist[tid] = 0;
        __syncthreads();
        for (int e = bb * 256 + tid; e < E; e += 512 * 256)
            atomicAdd(&lhist[e_dst[e] >> 8], 1);
        __syncthreads();
        if (tid < nb && lhist[tid]) atomicAdd(&bh[tid], lhist[tid]);
    }
}

// single block: exclusive scan of nb bucket counts -> bucket_base[0..nb], cursor copy
__global__ __launch_bounds__(256) void k_bscan(const int* __restrict__ bh, int nb, int Etot,
                                               int* __restrict__ bucket_base,
                                               int* __restrict__ bucket_cursor,
                                               int* __restrict__ row_start, int Nn) {
    __shared__ int wsum[4];
    int t = threadIdx.x, lane = t & 63, wid = t >> 6;
    int v = (t < nb) ? bh[t] : 0;
    int x = v;
    #pragma unroll
    for (int off = 1; off < 64; off <<= 1) {
        int s = __shfl_up(x, off, 64);
        if (lane >= off) x += s;
    }
    if (lane == 63) wsum[wid] = x;
    __syncthreads();
    if (t == 0) {
        int run = 0;
        #pragma unroll
        for (int wv = 0; wv < 4; ++wv) { int s = wsum[wv]; wsum[wv] = run; run += s; }
    }
    __syncthreads();
    int excl = wsum[wid] + x - v;
    if (t < nb) { bucket_base[t] = excl; bucket_cursor[t] = excl; }
    if (t == 0) { bucket_base[nb] = Etot; row_start[Nn] = Etot; }
}

// phase A: bin edges by bucket (dst>>8) via LDS staging; coalesced run writes.
// record: .x = src | (dst<<16), .y = weight bits
#define ACHUNK 4096

__global__ __launch_bounds__(256) void k_binA(const int* __restrict__ src,
                                              const int* __restrict__ dst,
                                              const float* __restrict__ ew, int E,
                                              int* __restrict__ bucket_cursor,
                                              uint2* __restrict__ s_tmp) {
    __shared__ uint2 s_rec[ACHUNK];
    __shared__ int hist[256], lstart[256], cur[256], gpos[256];
    __shared__ int wsum[4];
    int tid = threadIdx.x, lane = tid & 63, wid = tid >> 6;
    int base = blockIdx.x * ACHUNK;
    int cnt = E - base; if (cnt > ACHUNK) cnt = ACHUNK;
    hist[tid] = 0;
    __syncthreads();
    for (int i = tid; i < cnt; i += 256)
        atomicAdd(&hist[dst[base + i] >> 8], 1);
    __syncthreads();
    // exclusive scan of hist -> lstart
    {
        int v = hist[tid];
        int x = v;
        #pragma unroll
        for (int off = 1; off < 64; off <<= 1) {
            int s = __shfl_up(x, off, 64);
            if (lane >= off) x += s;
        }
        if (lane == 63) wsum[wid] = x;
        __syncthreads();
        if (tid == 0) {
            int run = 0;
            #pragma unroll
            for (int wv = 0; wv < 4; ++wv) { int s = wsum[wv]; wsum[wv] = run; run += s; }
        }
        __syncthreads();
        int excl = wsum[wid] + x - v;
        lstart[tid] = excl;
        cur[tid] = excl;
    }
    __syncthreads();
    // place records into LDS ordered by bucket
    for (int i = tid; i < cnt; i += 256) {
        int d = dst[base + i];
        int r = atomicAdd(&cur[d >> 8], 1);
        uint2 rec;
        rec.x = (unsigned)src[base + i] | ((unsigned)d << 16);
        rec.y = __float_as_uint(ew[base + i]);
        s_rec[r] = rec;
    }
    __syncthreads();
    // reserve global space per bucket
    {
        int c = cur[tid] - lstart[tid];
        gpos[tid] = c ? atomicAdd(&bucket_cursor[tid], c) : 0;
    }
    __syncthreads();
    // coalesced run copy-out
    for (int i = tid; i < cnt; i += 256) {
        uint2 rec = s_rec[i];
        int bk = rec.x >> 24;
        s_tmp[gpos[bk] + (i - lstart[bk])] = rec;
    }
}

// phase B: per-bucket exact counting sort by dst low byte, fully in LDS.
#define BCAP 6144

__global__ __launch_bounds__(256) void k_binB(const uint2* __restrict__ s_tmp,
                                              const int* __restrict__ bucket_base,
                                              uint2* __restrict__ s_edge,
                                              int* __restrict__ row_start, int Nn) {
    __shared__ uint2 s_out[BCAP];
    __shared__ int hist[256], excl[256], cur[256];
    __shared__ int wsum[4];
    int tid = threadIdx.x, lane = tid & 63, wid = tid >> 6;
    int b = blockIdx.x;
    int beg = bucket_base[b], cnt = bucket_base[b + 1] - beg;
    hist[tid] = 0;
    __syncthreads();
    for (int i = tid; i < cnt; i += 256)
        atomicAdd(&hist[(s_tmp[beg + i].x >> 16) & 255], 1);
    __syncthreads();
    {
        int v = hist[tid];
        int x = v;
        #pragma unroll
        for (int off = 1; off < 64; off <<= 1) {
            int s = __shfl_up(x, off, 64);
            if (lane >= off) x += s;
        }
        if (lane == 63) wsum[wid] = x;
        __syncthreads();
        if (tid == 0) {
            int run = 0;
            #pragma unroll
            for (int wv = 0; wv < 4; ++wv) { int s = wsum[wv]; wsum[wv] = run; run += s; }
        }
        __syncthreads();
        int e = wsum[wid] + x - v;
        excl[tid] = e;
        cur[tid] = e;
        int node = (b << 8) + tid;
        if (node < Nn) row_start[node] = beg + e;
    }
    __syncthreads();
    if (cnt <= BCAP) {
        for (int i = tid; i < cnt; i += 256) {
            uint2 rec = s_tmp[beg + i];
            int r = atomicAdd(&cur[(rec.x >> 16) & 255], 1);
            uint2 o; o.x = rec.x & 0xffffu; o.y = rec.y;
            s_out[r] = o;
        }
        __syncthreads();
        for (int i = tid; i < cnt; i += 256)
            s_edge[beg + i] = s_out[i];
    } else {
        // overflow fallback (statistically unreachable for uniform graphs)
        for (int i = tid; i < cnt; i += 256) {
            uint2 rec = s_tmp[beg + i];
            int r = atomicAdd(&cur[(rec.x >> 16) & 255], 1);
            uint2 o; o.x = rec.x & 0xffffu; o.y = rec.y;
            s_edge[beg + r] = o;
        }
    }
}

// ---------------- aggregation (bf16 h, packed edges) ----------------

__global__ __launch_bounds__(256) void k_agg(const bfu* __restrict__ h,
                                             const int* __restrict__ row_start,
                                             const uint2* __restrict__ s_edge,
                                             bfu* __restrict__ agg, int Nn) {
    int node = (int)((blockIdx.x * blockDim.x + threadIdx.x) >> 6);
    int lane = threadIdx.x & 63;
    if (node >= Nn) return;
    int beg = row_start[node], end = row_start[node + 1];
    const uint2* hv = (const uint2*)h;
    float a0 = 0.f, a1 = 0.f, a2 = 0.f, a3 = 0.f;
    int e = beg;
    for (; e + 3 < end; e += 4) {
        uint2 p0 = s_edge[e], p1 = s_edge[e + 1], p2 = s_edge[e + 2], p3 = s_edge[e + 3];
        uint2 v0 = hv[(size_t)p0.x * 64 + lane];
        uint2 v1 = hv[(size_t)p1.x * 64 + lane];
        uint2 v2 = hv[(size_t)p2.x * 64 + lane];
        uint2 v3 = hv[(size_t)p3.x * 64 + lane];
        float w0 = __uint_as_float(p0.y), w1 = __uint_as_float(p1.y);
        float w2 = __uint_as_float(p2.y), w3 = __uint_as_float(p3.y);
        a0 += w0 * bf2f(v0.x & 0xffffu) + w1 * bf2f(v1.x & 0xffffu)
            + w2 * bf2f(v2.x & 0xffffu) + w3 * bf2f(v3.x & 0xffffu);
        a1 += w0 * bf2f(v0.x >> 16) + w1 * bf2f(v1.x >> 16)
            + w2 * bf2f(v2.x >> 16) + w3 * bf2f(v3.x >> 16);
        a2 += w0 * bf2f(v0.y & 0xffffu) + w1 * bf2f(v1.y & 0xffffu)
            + w2 * bf2f(v2.y & 0xffffu) + w3 * bf2f(v3.y & 0xffffu);
        a3 += w0 * bf2f(v0.y >> 16) + w1 * bf2f(v1.y >> 16)
            + w2 * bf2f(v2.y >> 16) + w3 * bf2f(v3.y >> 16);
    }
    for (; e < end; ++e) {
        uint2 p0 = s_edge[e];
        float w0 = __uint_as_float(p0.y);
        uint2 v0 = hv[(size_t)p0.x * 64 + lane];
        a0 += w0 * bf2f(v0.x & 0xffffu);
        a1 += w0 * bf2f(v0.x >> 16);
        a2 += w0 * bf2f(v0.y & 0xffffu);
        a3 += w0 * bf2f(v0.y >> 16);
    }
    uint2 o;
    o.x = (unsigned)f2bf(a0) | ((unsigned)f2bf(a1) << 16);
    o.y = (unsigned)f2bf(a2) | ((unsigned)f2bf(a3) << 16);
    ((uint2*)agg)[(size_t)node * 64 + lane] = o;
}

// ---------------- bf16 MFMA GEMM (64x64 tile) with fused column stats ----------------
#define BM 64
#define BN 64
#define BK 32

__global__ __launch_bounds__(256) void gemm_mfma(
    const bfu* __restrict__ A1, int K1, const bfu* __restrict__ W1t,
    const bfu* __restrict__ A2, int K2, const bfu* __restrict__ W2t,
    const float* __restrict__ bias, bfu* __restrict__ out,
    float* __restrict__ stats, int M, int Ncols) {
    __shared__ bfu lds[64 * 72];
    __shared__ float sstat[128];
    bfu* As = lds;
    bfu* Bs = lds + 2048;
    bfu* Ct = lds;
    int tid = threadIdx.x;
    int lane = tid & 63;
    int w = tid >> 6;
    int wm = (w >> 1) * 32;
    int wn = (w & 1) * 32;
    int row0 = blockIdx.y * BM;
    int col0 = blockIdx.x * BN;

    if (tid < 128) sstat[tid] = 0.f;

    f32x4 acc[2][2];
    #pragma unroll
    for (int i = 0; i < 2; ++i)
        #pragma unroll
        for (int j = 0; j < 2; ++j) acc[i][j] = (f32x4)(0.f);

    int sr = w * 16 + (lane >> 2);
    int sg = ((lane & 3) - (sr >> 1)) & 3;
    size_t soff = (size_t)sr;
    int scol = sg * 8;

    int rsel = lane & 15;
    int kg = lane >> 4;

    const int KT = K1 + K2;
    for (int k0 = 0; k0 < KT; k0 += BK) {
        const bfu* A; const bfu* Wt; int K; int kk;
        if (k0 < K1) { A = A1; Wt = W1t; K = K1; kk = k0; }
        else         { A = A2; Wt = W2t; K = K2; kk = k0 - K1; }
        __syncthreads();
        GLOBAL_LOAD_LDS16(A  + ((size_t)(row0) + soff) * K + kk + scol, As + w * 512);
        GLOBAL_LOAD_LDS16(Wt + ((size_t)(col0) + soff) * K + kk + scol, Bs + w * 512);
        __syncthreads();

        bf16x8 af[2], bfr[2];
        #pragma unroll
        for (int i = 0; i < 2; ++i) {
            int rr = wm + i * 16 + rsel;
            int gs = (kg + (rr >> 1)) & 3;
            af[i] = *(const bf16x8*)&As[rr * 32 + gs * 8];
        }
        #pragma unroll
        for (int j = 0; j < 2; ++j) {
            int nn = wn + j * 16 + rsel;
            int gs = (kg + (nn >> 1)) & 3;
            bfr[j] = *(const bf16x8*)&Bs[nn * 32 + gs * 8];
        }
        #pragma unroll
        for (int i = 0; i < 2; ++i)
            #pragma unroll
            for (int j = 0; j < 2; ++j)
                acc[i][j] = __builtin_amdgcn_mfma_f32_16x16x32_bf16(af[i], bfr[j], acc[i][j], 0, 0, 0);
    }

    __syncthreads();

    int lgrp = lane >> 4;
    #pragma unroll
    for (int j = 0; j < 2; ++j) {
        int ccol = wn + j * 16 + rsel;
        float bv = bias[col0 + ccol];
        float s = 0.f, s2 = 0.f;
        #pragma unroll
        for (int i = 0; i < 2; ++i) {
            int rrb = wm + i * 16 + lgrp * 4;
            #pragma unroll
            for (int r = 0; r < 4; ++r) {
                int rr = rrb + r;
                float v = acc[i][j][r] + bv;
                Ct[rr * 72 + ccol] = f2bf(v);
                if (row0 + rr < M) { s += v; s2 += v * v; }
            }
        }
        s  += __shfl_xor(s, 16, 64);  s  += __shfl_xor(s, 32, 64);
        s2 += __shfl_xor(s2, 16, 64); s2 += __shfl_xor(s2, 32, 64);
        if (lgrp == 0) {
            atomicAdd(&sstat[ccol], s);
            atomicAdd(&sstat[64 + ccol], s2);
        }
    }
    __syncthreads();

    if (tid < 128) {
        int c = tid & 63;
        float v = sstat[tid];
        if (tid < 64) atomicAdd(&stats[col0 + c], v);
        else          atomicAdd(&stats[D + col0 + c], v);
    }

    int r = tid >> 2, cq = (tid & 3) * 16;
    if (row0 + r < M) {
        uint4 a = *(const uint4*)&Ct[r * 72 + cq];
        uint4 b = *(const uint4*)&Ct[r * 72 + cq + 8];
        uint4* gp = (uint4*)&out[(size_t)(row0 + r) * Ncols + col0 + cq];
        gp[0] = a;
        gp[1] = b;
    }
}

// ---------------- BN apply (pre + conv layers), bf16 in/out ----------------

__global__ __launch_bounds__(256) void bn_prelu_bf16(const bfu* __restrict__ hf,
                                                     const float* __restrict__ stats,
                                                     const float* __restrict__ g,
                                                     const float* __restrict__ be,
                                                     const float* __restrict__ a_ptr,
                                                     bfu* __restrict__ hb,
                                                     int total4, int Nrows) {
    int idx = blockIdx.x * 256 + threadIdx.x;
    if (idx >= total4) return;
    float a = a_ptr[0];
    float inv = 1.0f / (float)Nrows;
    int c4 = (idx & 63) * 4;
    uint2 v = ((const uint2*)hf)[idx];
    float vin[4] = {bf2f(v.x & 0xffffu), bf2f(v.x >> 16),
                    bf2f(v.y & 0xffffu), bf2f(v.y >> 16)};
    bfu o[4];
    #pragma unroll
    for (int t = 0; t < 4; ++t) {
        int c = c4 + t;
        float m = stats[c] * inv;
        float var = stats[D + c] * inv - m * m;
        float sc = rsqrtf(var + EPS) * g[c];
        float sh = be[c] - m * sc;
        float u = vin[t] * sc + sh;
        o[t] = f2bf(u >= 0.f ? u : a * u);
    }
    uint2 ov;
    ov.x = (unsigned)o[0] | ((unsigned)o[1] << 16);
    ov.y = (unsigned)o[2] | ((unsigned)o[3] << 16);
    ((uint2*)hb)[idx] = ov;
}

// ---------------- fused post-BN + PReLU + head dot ----------------

__global__ __launch_bounds__(256) void k_final_fused(
    const float* __restrict__ x, const bfu* __restrict__ outf,
    const float* __restrict__ stats, const float* __restrict__ g,
    const float* __restrict__ be, const float* __restrict__ a_ptr,
    const float* __restrict__ Wf, const float* __restrict__ bf_,
    float* __restrict__ z, int Nn, int Nrows) {
    int node = (int)((blockIdx.x * blockDim.x + threadIdx.x) >> 6);
    int lane = threadIdx.x & 63;
    if (node >= Nn) return;
    float a = a_ptr[0];
    float inv = 1.0f / (float)Nrows;
    float s = x[(size_t)node * F_IN + lane] * Wf[lane]
            + x[(size_t)node * F_IN + 64 + lane] * Wf[64 + lane];
    uint2 v  = ((const uint2*)outf)[(size_t)node * 64 + lane];
    float4 wv = ((const float4*)(Wf + F_IN))[lane];
    float4 st1 = ((const float4*)stats)[lane];
    float4 st2 = ((const float4*)(stats + D))[lane];
    float4 gv = ((const float4*)g)[lane];
    float4 bev = ((const float4*)be)[lane];
    float vin[4] = {bf2f(v.x & 0xffffu), bf2f(v.x >> 16),
                    bf2f(v.y & 0xffffu), bf2f(v.y >> 16)};
    float m1[4] = {st1.x, st1.y, st1.z, st1.w};
    float m2[4] = {st2.x, st2.y, st2.z, st2.w};
    float gg[4] = {gv.x, gv.y, gv.z, gv.w};
    float bb[4] = {bev.x, bev.y, bev.z, bev.w};
    float ww[4] = {wv.x, wv.y, wv.z, wv.w};
    #pragma unroll
    for (int t = 0; t < 4; ++t) {
        float m = m1[t] * inv;
        float var = m2[t] * inv - m * m;
        float sc = rsqrtf(var + EPS) * gg[t];
        float sh = bb[t] - m * sc;
        float u = vin[t] * sc + sh;
        u = u >= 0.f ? u : a * u;
        s += u * ww[t];
    }
    #pragma unroll
    for (int off = 32; off; off >>= 1) s += __shfl_down(s, off, 64);
    if (lane == 0) z[node] = s + bf_[0];
}

__global__ __launch_bounds__(256) void k_zstats(const float* __restrict__ z,
                                                float* __restrict__ zs, int n) {
    float s = 0.f, s2 = 0.f;
    for (int i = blockIdx.x * blockDim.x + threadIdx.x; i < n; i += gridDim.x * blockDim.x) {
        float v = z[i];
        s += v; s2 += v * v;
    }
    #pragma unroll
    for (int off = 32; off; off >>= 1) {
        s += __shfl_down(s, off, 64);
        s2 += __shfl_down(s2, off, 64);
    }
    __shared__ float ws[4], ws2[4];
    int lane = threadIdx.x & 63, wid = threadIdx.x >> 6;
    if (lane == 0) { ws[wid] = s; ws2[wid] = s2; }
    __syncthreads();
    if (threadIdx.x == 0) {
        atomicAdd(&zs[0], ws[0] + ws[1] + ws[2] + ws[3]);
        atomicAdd(&zs[1], ws2[0] + ws2[1] + ws2[2] + ws2[3]);
    }
}

__global__ __launch_bounds__(256) void k_logsm(const float* __restrict__ z,
                                               const float* __restrict__ zs,
                                               const float* __restrict__ g,
                                               const float* __restrict__ be,
                                               const float* __restrict__ a_ptr,
                                               float* __restrict__ out, int C, int Ntot) {
    __shared__ float red[4], red2[4];
    int t = threadIdx.x;
    int lane = t & 63, wid = t >> 6;
    float mean = zs[0] / (float)Ntot;
    float var = zs[1] / (float)Ntot - mean * mean;
    float sc = rsqrtf(var + EPS) * g[0];
    float sh = be[0] - mean * sc;
    float a = a_ptr[0];
    const float* zg = z + (size_t)blockIdx.x * C;
    float vals[4];
    int cnt = 0;
    float mx = -3.4e38f;
    for (int i = t; i < C; i += 256) {
        float u = zg[i] * sc + sh;
        u = u >= 0.f ? u : a * u;
        vals[cnt++] = u;
        mx = fmaxf(mx, u);
    }
    #pragma unroll
    for (int off = 32; off; off >>= 1) mx = fmaxf(mx, __shfl_down(mx, off, 64));
    if (lane == 0) red[wid] = mx;
    __syncthreads();
    float M4 = fmaxf(fmaxf(red[0], red[1]), fmaxf(red[2], red[3]));
    float se = 0.f;
    for (int j = 0; j < cnt; ++j) se += expf(vals[j] - M4);
    #pragma unroll
    for (int off = 32; off; off >>= 1) se += __shfl_down(se, off, 64);
    if (lane == 0) red2[wid] = se;
    __syncthreads();
    float S4 = red2[0] + red2[1] + red2[2] + red2[3];
    float lse = logf(S4) + M4;
    cnt = 0;
    for (int i = t; i < C; i += 256) out[(size_t)blockIdx.x * C + i] = vals[cnt++] - lse;
}

// ---------------- launch ----------------

extern "C" void kernel_launch(void* const* d_in, const int* in_sizes, int n_in,
                              void* d_out, int out_size, void* d_ws, size_t ws_size,
                              hipStream_t stream) {
    const float* x      = (const float*)d_in[0];
    const int*   eidx   = (const int*)d_in[1];
    const float* e_w    = (const float*)d_in[2];
    const float* W_pre  = (const float*)d_in[4];
    const float* b_pre  = (const float*)d_in[5];
    const float* g_pre  = (const float*)d_in[6];
    const float* be_pre = (const float*)d_in[7];
    const float* a_pre  = (const float*)d_in[8];
    const float* W_rel  = (const float*)d_in[9];
    const float* b_rel  = (const float*)d_in[10];
    const float* W_root = (const float*)d_in[11];
    const float* g_conv = (const float*)d_in[12];
    const float* be_conv= (const float*)d_in[13];
    const float* a_conv = (const float*)d_in[14];
    const float* W_post = (const float*)d_in[15];
    const float* b_post = (const float*)d_in[16];
    const float* g_post = (const float*)d_in[17];
    const float* be_post= (const float*)d_in[18];
    const float* a_post = (const float*)d_in[19];
    const float* W_fin  = (const float*)d_in[20];
    const float* b_fin  = (const float*)d_in[21];
    const float* g_fin  = (const float*)d_in[22];
    const float* be_fin = (const float*)d_in[23];
    const float* a_fin  = (const float*)d_in[24];

    const int N = in_sizes[0] / F_IN;   // 50000
    const int E = in_sizes[2];          // 800000
    const int L = in_sizes[14];         // 3
    const int Npad = ((N + BM - 1) / BM) * BM;
    const int NB = (N + 255) >> 8;      // node buckets (196)
    const int* e_src = eidx;
    const int* e_dst = eidx + E;

    uint8_t* wsp = (uint8_t*)d_ws;
    size_t used = 0;
    auto alloc = [&](size_t bytes) -> void* {
        void* p = wsp + used;
        used += (bytes + 255) & ~(size_t)255;
        return p;
    };
    bfu*   xb       = (bfu*)alloc((size_t)Npad * F_IN * 2);
    bfu*   hb0      = (bfu*)alloc((size_t)Npad * D * 2);
    bfu*   hb1      = (bfu*)alloc((size_t)Npad * D * 2);
    bfu*   aggb     = (bfu*)alloc((size_t)Npad * D * 2);
    bfu*   outb     = (bfu*)alloc((size_t)N * D * 2);
    bfu*   Wt_pre   = (bfu*)alloc((size_t)D * F_IN * 2);
    bfu*   Wt_rel   = (bfu*)alloc((size_t)L * D * D * 2);
    bfu*   Wt_root  = (bfu*)alloc((size_t)L * D * D * 2);
    bfu*   Wt_post  = (bfu*)alloc((size_t)D * D * 2);
    float* z        = (float*)alloc((size_t)N * 4);
    float* statsall = (float*)alloc((size_t)(5 * 2 * D + 2) * 4);
    int*   bh       = (int*)alloc((size_t)NB * 4);
    int*   bucket_base   = (int*)alloc((size_t)(NB + 1) * 4);
    int*   bucket_cursor = (int*)alloc((size_t)NB * 4);
    int*   row_start= (int*)alloc((size_t)(N + 1) * 4);
    uint2* s_tmp    = (uint2*)alloc((size_t)E * 8);
    uint2* s_edge   = (uint2*)alloc((size_t)E * 8);
    if (used > ws_size) {
        fprintf(stderr, "kernel_launch: ws too small (%zu > %zu)\n", used, ws_size);
        return;
    }
    float* st_pre  = statsall;
    float* st_post = statsall + 4 * 2 * D;
    float* zstats  = statsall + 5 * 2 * D;

    hipMemsetAsync(bh, 0, (size_t)NB * 4, stream);
    hipMemsetAsync(statsall, 0, (size_t)(5 * 2 * D + 2) * 4, stream);

    // front end: cvt + transposes + bucket histogram (one launch)
    const int total4 = N * (F_IN / 4);
    const int CVT_BLOCKS = (total4 + 255) / 256;
    k_front<<<CVT_BLOCKS + 2048 + 512, 256, 0, stream>>>(
        x, e_dst, W_pre, W_rel, W_root, W_post,
        xb, Wt_pre, Wt_rel, Wt_root, Wt_post, bh, CVT_BLOCKS, E, NB, total4);

    // hierarchical counting sort
    k_bscan<<<1, 256, 0, stream>>>(bh, NB, E, bucket_base, bucket_cursor, row_start, N);
    k_binA<<<(E + ACHUNK - 1) / ACHUNK, 256, 0, stream>>>(e_src, e_dst, e_w, E,
                                                          bucket_cursor, s_tmp);
    k_binB<<<NB, 256, 0, stream>>>(s_tmp, bucket_base, s_edge, row_start, N);

    dim3 gg(D / BN, Npad / BM);
    const int bn_blocks = (N * (D / 4) + 255) / 256;
    const int wave_blocks = (N + 3) / 4;

    // preprocess
    gemm_mfma<<<gg, 256, 0, stream>>>(xb, F_IN, Wt_pre, nullptr, 0, nullptr,
                                      b_pre, outb, st_pre, N, D);
    bn_prelu_bf16<<<bn_blocks, 256, 0, stream>>>(outb, st_pre, g_pre, be_pre, a_pre,
                                                 hb0, N * (D / 4), N);

    bfu* hc = hb0;
    bfu* hn = hb1;
    for (int l = 0; l < L; ++l) {
        float* st = statsall + (1 + l) * 2 * D;
        k_agg<<<wave_blocks, 256, 0, stream>>>(hc, row_start, s_edge, aggb, N);
        gemm_mfma<<<gg, 256, 0, stream>>>(aggb, D, Wt_rel + (size_t)l * D * D,
                                          hc, D, Wt_root + (size_t)l * D * D,
                                          b_rel + (size_t)l * D, outb, st, N, D);
        bn_prelu_bf16<<<bn_blocks, 256, 0, stream>>>(outb, st, g_conv + (size_t)l * D,
                                                     be_conv + (size_t)l * D, a_conv + l,
                                                     hn, N * (D / 4), N);
        bfu* tmp = hc; hc = hn; hn = tmp;
    }

    // postprocess gemm (stats fused) -> fused BN+PReLU+head dot
    gemm_mfma<<<gg, 256, 0, stream>>>(hc, D, Wt_post, nullptr, 0, nullptr,
                                      b_post, outb, st_post, N, D);
    k_final_fused<<<wave_blocks, 256, 0, stream>>>(x, outb, st_post, g_post, be_post,
                                                   a_post, W_fin, b_fin, z, N, N);
    k_zstats<<<64, 256, 0, stream>>>(z, zstats, N);
    k_logsm<<<N / 1000, 256, 0, stream>>>(z, zstats, g_fin, be_fin, a_fin,
                                          (float*)d_out, 1000, N);
}

// Round 6
// 577.231 us; speedup vs baseline: 2.9547x; 1.0548x over previous
//
#include <hip/hip_runtime.h>
#include <cstdio>
#include <cstdint>

#define F_IN 128
#define D 256
#define EPS 1e-5f
// N must be < 65536 for the 16-bit src/dst packing in the edge sort (N=50000).

typedef unsigned short bfu;
typedef __attribute__((ext_vector_type(8))) short bf16x8;
typedef __attribute__((ext_vector_type(4))) float f32x4;

__device__ __forceinline__ float bf2f(unsigned u) {
    return __uint_as_float(u << 16);
}
__device__ __forceinline__ bfu f2bf(float f) {
    unsigned u = __float_as_uint(f);
    return (bfu)((u + 0x7fffu + ((u >> 16) & 1u)) >> 16);
}

#define GLOBAL_LOAD_LDS16(gp, lp)                                                  \
    __builtin_amdgcn_global_load_lds((const __attribute__((address_space(1))) void*)(gp), \
                                     (__attribute__((address_space(3))) void*)(lp), 16, 0, 0)

// ---------------- front end: cvt + weight transposes + bucket histogram ----------------

__global__ __launch_bounds__(256) void k_front(
    const float* __restrict__ x, const int* __restrict__ e_dst,
    const float* __restrict__ Wp, const float* __restrict__ Wr,
    const float* __restrict__ Wo, const float* __restrict__ Ws,
    bfu* __restrict__ xb, bfu* __restrict__ Tp, bfu* __restrict__ Tr,
    bfu* __restrict__ To, bfu* __restrict__ Ts,
    int* __restrict__ bh, int cvt_blocks, int E, int nb, int total4) {
    int b = blockIdx.x;
    int tid = threadIdx.x;
    if (b < cvt_blocks) {
        int idx = b * 256 + tid;
        if (idx >= total4) return;
        float4 v = ((const float4*)x)[idx];
        uint2 o;
        o.x = (unsigned)f2bf(v.x) | ((unsigned)f2bf(v.y) << 16);
        o.y = (unsigned)f2bf(v.z) | ((unsigned)f2bf(v.w) << 16);
        ((uint2*)xb)[idx] = o;
    } else if (b < cvt_blocks + 2048) {
        int tb = b - cvt_blocks;
        int region = tb >> 8;
        const float* S; bfu* Dst; int K;
        if (region == 0)      { S = Wp;                        Dst = Tp;                        K = F_IN; }
        else if (region <= 3) { S = Wr + (region - 1) * D * D; Dst = Tr + (region - 1) * D * D; K = D; }
        else if (region <= 6) { S = Wo + (region - 4) * D * D; Dst = To + (region - 4) * D * D; K = D; }
        else                  { S = Ws;                        Dst = Ts;                        K = D; }
        int idx = (tb & 255) * 256 + tid;
        if (idx >= K * D) return;
        int n = idx / K, k = idx % K;
        Dst[idx] = f2bf(S[(size_t)k * D + n]);
    } else {
        __shared__ int lhist[256];
        int bb = b - cvt_blocks - 2048;
        lhist[tid] = 0;
        __syncthreads();
        for (int e = bb * 256 + tid; e < E; e += 512 * 256)
            atomicAdd(&lhist[e_dst[e] >> 8], 1);
        __syncthreads();
        if (tid < nb && lhist[tid]) atomicAdd(&bh[tid], lhist[tid]);
    }
}

__global__ __launch_bounds__(256) void k_bscan(const int* __restrict__ bh, int nb, int Etot,
                                               int* __restrict__ bucket_base,
                                               int* __restrict__ bucket_cursor,
                                               int* __restrict__ row_start, int Nn) {
    __shared__ int wsum[4];
    int t = threadIdx.x, lane = t & 63, wid = t >> 6;
    int v = (t < nb) ? bh[t] : 0;
    int x = v;
    #pragma unroll
    for (int off = 1; off < 64; off <<= 1) {
        int s = __shfl_up(x, off, 64);
        if (lane >= off) x += s;
    }
    if (lane == 63) wsum[wid] = x;
    __syncthreads();
    if (t == 0) {
        int run = 0;
        #pragma unroll
        for (int wv = 0; wv < 4; ++wv) { int s = wsum[wv]; wsum[wv] = run; run += s; }
    }
    __syncthreads();
    int excl = wsum[wid] + x - v;
    if (t < nb) { bucket_base[t] = excl; bucket_cursor[t] = excl; }
    if (t == 0) { bucket_base[nb] = Etot; row_start[Nn] = Etot; }
}

#define ACHUNK 4096

__global__ __launch_bounds__(256) void k_binA(const int* __restrict__ src,
                                              const int* __restrict__ dst,
                                              const float* __restrict__ ew, int E,
                                              int* __restrict__ bucket_cursor,
                                              uint2* __restrict__ s_tmp) {
    __shared__ uint2 s_rec[ACHUNK];
    __shared__ int hist[256], lstart[256], cur[256], gpos[256];
    __shared__ int wsum[4];
    int tid = threadIdx.x, lane = tid & 63, wid = tid >> 6;
    int base = blockIdx.x * ACHUNK;
    int cnt = E - base; if (cnt > ACHUNK) cnt = ACHUNK;
    hist[tid] = 0;
    __syncthreads();
    for (int i = tid; i < cnt; i += 256)
        atomicAdd(&hist[dst[base + i] >> 8], 1);
    __syncthreads();
    {
        int v = hist[tid];
        int x = v;
        #pragma unroll
        for (int off = 1; off < 64; off <<= 1) {
            int s = __shfl_up(x, off, 64);
            if (lane >= off) x += s;
        }
        if (lane == 63) wsum[wid] = x;
        __syncthreads();
        if (tid == 0) {
            int run = 0;
            #pragma unroll
            for (int wv = 0; wv < 4; ++wv) { int s = wsum[wv]; wsum[wv] = run; run += s; }
        }
        __syncthreads();
        int excl = wsum[wid] + x - v;
        lstart[tid] = excl;
        cur[tid] = excl;
    }
    __syncthreads();
    for (int i = tid; i < cnt; i += 256) {
        int d = dst[base + i];
        int r = atomicAdd(&cur[d >> 8], 1);
        uint2 rec;
        rec.x = (unsigned)src[base + i] | ((unsigned)d << 16);
        rec.y = __float_as_uint(ew[base + i]);
        s_rec[r] = rec;
    }
    __syncthreads();
    {
        int c = cur[tid] - lstart[tid];
        gpos[tid] = c ? atomicAdd(&bucket_cursor[tid], c) : 0;
    }
    __syncthreads();
    for (int i = tid; i < cnt; i += 256) {
        uint2 rec = s_rec[i];
        int bk = rec.x >> 24;
        s_tmp[gpos[bk] + (i - lstart[bk])] = rec;
    }
}

#define BCAP 6144

__global__ __launch_bounds__(256) void k_binB(const uint2* __restrict__ s_tmp,
                                              const int* __restrict__ bucket_base,
                                              uint2* __restrict__ s_edge,
                                              int* __restrict__ row_start, int Nn) {
    __shared__ uint2 s_out[BCAP];
    __shared__ int hist[256], excl[256], cur[256];
    __shared__ int wsum[4];
    int tid = threadIdx.x, lane = tid & 63, wid = tid >> 6;
    int b = blockIdx.x;
    int beg = bucket_base[b], cnt = bucket_base[b + 1] - beg;
    hist[tid] = 0;
    __syncthreads();
    for (int i = tid; i < cnt; i += 256)
        atomicAdd(&hist[(s_tmp[beg + i].x >> 16) & 255], 1);
    __syncthreads();
    {
        int v = hist[tid];
        int x = v;
        #pragma unroll
        for (int off = 1; off < 64; off <<= 1) {
            int s = __shfl_up(x, off, 64);
            if (lane >= off) x += s;
        }
        if (lane == 63) wsum[wid] = x;
        __syncthreads();
        if (tid == 0) {
            int run = 0;
            #pragma unroll
            for (int wv = 0; wv < 4; ++wv) { int s = wsum[wv]; wsum[wv] = run; run += s; }
        }
        __syncthreads();
        int e = wsum[wid] + x - v;
        excl[tid] = e;
        cur[tid] = e;
        int node = (b << 8) + tid;
        if (node < Nn) row_start[node] = beg + e;
    }
    __syncthreads();
    if (cnt <= BCAP) {
        for (int i = tid; i < cnt; i += 256) {
            uint2 rec = s_tmp[beg + i];
            int r = atomicAdd(&cur[(rec.x >> 16) & 255], 1);
            uint2 o; o.x = rec.x & 0xffffu; o.y = rec.y;
            s_out[r] = o;
        }
        __syncthreads();
        for (int i = tid; i < cnt; i += 256)
            s_edge[beg + i] = s_out[i];
    } else {
        for (int i = tid; i < cnt; i += 256) {
            uint2 rec = s_tmp[beg + i];
            int r = atomicAdd(&cur[(rec.x >> 16) & 255], 1);
            uint2 o; o.x = rec.x & 0xffffu; o.y = rec.y;
            s_edge[beg + r] = o;
        }
    }
}

// ---------------- aggregation: uint4 gathers, 2 edges/wave in lane-halves ----------------

__global__ __launch_bounds__(256) void k_agg(const bfu* __restrict__ h,
                                             const int* __restrict__ row_start,
                                             const uint2* __restrict__ s_edge,
                                             bfu* __restrict__ agg, int Nn) {
    int node = (int)((blockIdx.x * blockDim.x + threadIdx.x) >> 6);
    int lane = threadIdx.x & 63;
    if (node >= Nn) return;
    int half = lane >> 5;      // 0: even tail-slot edges, 1: odd
    int l2 = lane & 31;        // 16B chunk within the 512B row
    int beg = row_start[node], end = row_start[node + 1];
    const uint4* hv = (const uint4*)h;   // row = 32 uint4
    float acc[8];
    #pragma unroll
    for (int k = 0; k < 8; ++k) acc[k] = 0.f;
    int e = beg;
    for (; e + 3 < end; e += 4) {
        uint2 p0 = s_edge[e + half];
        uint2 p1 = s_edge[e + 2 + half];
        uint4 v0 = hv[(size_t)p0.x * 32 + l2];
        uint4 v1 = hv[(size_t)p1.x * 32 + l2];
        float w0 = __uint_as_float(p0.y);
        float w1 = __uint_as_float(p1.y);
        unsigned u0[4] = {v0.x, v0.y, v0.z, v0.w};
        unsigned u1[4] = {v1.x, v1.y, v1.z, v1.w};
        #pragma unroll
        for (int k = 0; k < 4; ++k) {
            acc[2 * k]     += w0 * bf2f(u0[k] & 0xffffu);
            acc[2 * k + 1] += w0 * bf2f(u0[k] >> 16);
            acc[2 * k]     += w1 * bf2f(u1[k] & 0xffffu);
            acc[2 * k + 1] += w1 * bf2f(u1[k] >> 16);
        }
    }
    // tail (0..3 edges): half0 takes e, e+2; half1 takes e+1
    int idx = e + half;
    if (idx < end) {
        uint2 p = s_edge[idx];
        uint4 v = hv[(size_t)p.x * 32 + l2];
        float w = __uint_as_float(p.y);
        unsigned u[4] = {v.x, v.y, v.z, v.w};
        #pragma unroll
        for (int k = 0; k < 4; ++k) {
            acc[2 * k]     += w * bf2f(u[k] & 0xffffu);
            acc[2 * k + 1] += w * bf2f(u[k] >> 16);
        }
    }
    idx = e + 2;
    if (half == 0 && idx < end) {
        uint2 p = s_edge[idx];
        uint4 v = hv[(size_t)p.x * 32 + l2];
        float w = __uint_as_float(p.y);
        unsigned u[4] = {v.x, v.y, v.z, v.w};
        #pragma unroll
        for (int k = 0; k < 4; ++k) {
            acc[2 * k]     += w * bf2f(u[k] & 0xffffu);
            acc[2 * k + 1] += w * bf2f(u[k] >> 16);
        }
    }
    // cross-half reduce, half0 writes uint4
    #pragma unroll
    for (int k = 0; k < 8; ++k)
        acc[k] += __shfl_down(acc[k], 32, 64);
    if (half == 0) {
        uint4 o;
        o.x = (unsigned)f2bf(acc[0]) | ((unsigned)f2bf(acc[1]) << 16);
        o.y = (unsigned)f2bf(acc[2]) | ((unsigned)f2bf(acc[3]) << 16);
        o.z = (unsigned)f2bf(acc[4]) | ((unsigned)f2bf(acc[5]) << 16);
        o.w = (unsigned)f2bf(acc[6]) | ((unsigned)f2bf(acc[7]) << 16);
        ((uint4*)agg)[(size_t)node * 32 + l2] = o;
    }
}

// ---------------- bf16 MFMA GEMM (64x64 tile, XCD-swizzled grid) ----------------
// 1D grid = nrowblk*4 (nrowblk multiple of 8). bid -> xcd=bid&7, col=(bid>>3)&3,
// row=(bid>>5)*8+xcd: the 4 col-blocks of one row-tile run consecutively on ONE
// XCD so the shared A-tile stays in that XCD's L2.
#define BM 64
#define BN 64
#define BK 32

__global__ __launch_bounds__(256) void gemm_mfma(
    const bfu* __restrict__ A1, int K1, const bfu* __restrict__ W1t,
    const bfu* __restrict__ A2, int K2, const bfu* __restrict__ W2t,
    const float* __restrict__ bias, bfu* __restrict__ out,
    float* __restrict__ stats, int M, int Ncols) {
    __shared__ bfu lds[64 * 72];
    __shared__ float sstat[128];
    bfu* As = lds;
    bfu* Bs = lds + 2048;
    bfu* Ct = lds;
    int tid = threadIdx.x;
    int lane = tid & 63;
    int w = tid >> 6;
    int wm = (w >> 1) * 32;
    int wn = (w & 1) * 32;
    int bid = blockIdx.x;
    int xcd = bid & 7;
    int slot = bid >> 3;
    int row0 = ((slot >> 2) * 8 + xcd) * BM;
    int col0 = (slot & 3) * BN;

    if (tid < 128) sstat[tid] = 0.f;

    f32x4 acc[2][2];
    #pragma unroll
    for (int i = 0; i < 2; ++i)
        #pragma unroll
        for (int j = 0; j < 2; ++j) acc[i][j] = (f32x4)(0.f);

    int sr = w * 16 + (lane >> 2);
    int sg = ((lane & 3) - (sr >> 1)) & 3;
    size_t soff = (size_t)sr;
    int scol = sg * 8;

    int rsel = lane & 15;
    int kg = lane >> 4;

    const int KT = K1 + K2;
    for (int k0 = 0; k0 < KT; k0 += BK) {
        const bfu* A; const bfu* Wt; int K; int kk;
        if (k0 < K1) { A = A1; Wt = W1t; K = K1; kk = k0; }
        else         { A = A2; Wt = W2t; K = K2; kk = k0 - K1; }
        __syncthreads();
        GLOBAL_LOAD_LDS16(A  + ((size_t)(row0) + soff) * K + kk + scol, As + w * 512);
        GLOBAL_LOAD_LDS16(Wt + ((size_t)(col0) + soff) * K + kk + scol, Bs + w * 512);
        __syncthreads();

        bf16x8 af[2], bfr[2];
        #pragma unroll
        for (int i = 0; i < 2; ++i) {
            int rr = wm + i * 16 + rsel;
            int gs = (kg + (rr >> 1)) & 3;
            af[i] = *(const bf16x8*)&As[rr * 32 + gs * 8];
        }
        #pragma unroll
        for (int j = 0; j < 2; ++j) {
            int nn = wn + j * 16 + rsel;
            int gs = (kg + (nn >> 1)) & 3;
            bfr[j] = *(const bf16x8*)&Bs[nn * 32 + gs * 8];
        }
        #pragma unroll
        for (int i = 0; i < 2; ++i)
            #pragma unroll
            for (int j = 0; j < 2; ++j)
                acc[i][j] = __builtin_amdgcn_mfma_f32_16x16x32_bf16(af[i], bfr[j], acc[i][j], 0, 0, 0);
    }

    __syncthreads();

    int lgrp = lane >> 4;
    #pragma unroll
    for (int j = 0; j < 2; ++j) {
        int ccol = wn + j * 16 + rsel;
        float bv = bias[col0 + ccol];
        float s = 0.f, s2 = 0.f;
        #pragma unroll
        for (int i = 0; i < 2; ++i) {
            int rrb = wm + i * 16 + lgrp * 4;
            #pragma unroll
            for (int r = 0; r < 4; ++r) {
                int rr = rrb + r;
                float v = acc[i][j][r] + bv;
                Ct[rr * 72 + ccol] = f2bf(v);
                if (row0 + rr < M) { s += v; s2 += v * v; }
            }
        }
        s  += __shfl_xor(s, 16, 64);  s  += __shfl_xor(s, 32, 64);
        s2 += __shfl_xor(s2, 16, 64); s2 += __shfl_xor(s2, 32, 64);
        if (lgrp == 0) {
            atomicAdd(&sstat[ccol], s);
            atomicAdd(&sstat[64 + ccol], s2);
        }
    }
    __syncthreads();

    if (tid < 128) {
        int c = tid & 63;
        float v = sstat[tid];
        if (tid < 64) atomicAdd(&stats[col0 + c], v);
        else          atomicAdd(&stats[D + col0 + c], v);
    }

    int r = tid >> 2, cq = (tid & 3) * 16;
    if (row0 + r < M) {
        uint4 a = *(const uint4*)&Ct[r * 72 + cq];
        uint4 b = *(const uint4*)&Ct[r * 72 + cq + 8];
        uint4* gp = (uint4*)&out[(size_t)(row0 + r) * Ncols + col0 + cq];
        gp[0] = a;
        gp[1] = b;
    }
}

// ---------------- BN apply (pre + conv layers), bf16 in/out ----------------

__global__ __launch_bounds__(256) void bn_prelu_bf16(const bfu* __restrict__ hf,
                                                     const float* __restrict__ stats,
                                                     const float* __restrict__ g,
                                                     const float* __restrict__ be,
                                                     const float* __restrict__ a_ptr,
                                                     bfu* __restrict__ hb,
                                                     int total4, int Nrows) {
    int idx = blockIdx.x * 256 + threadIdx.x;
    if (idx >= total4) return;
    float a = a_ptr[0];
    float inv = 1.0f / (float)Nrows;
    int c4 = (idx & 63) * 4;
    uint2 v = ((const uint2*)hf)[idx];
    float vin[4] = {bf2f(v.x & 0xffffu), bf2f(v.x >> 16),
                    bf2f(v.y & 0xffffu), bf2f(v.y >> 16)};
    bfu o[4];
    #pragma unroll
    for (int t = 0; t < 4; ++t) {
        int c = c4 + t;
        float m = stats[c] * inv;
        float var = stats[D + c] * inv - m * m;
        float sc = rsqrtf(var + EPS) * g[c];
        float sh = be[c] - m * sc;
        float u = vin[t] * sc + sh;
        o[t] = f2bf(u >= 0.f ? u : a * u);
    }
    uint2 ov;
    ov.x = (unsigned)o[0] | ((unsigned)o[1] << 16);
    ov.y = (unsigned)o[2] | ((unsigned)o[3] << 16);
    ((uint2*)hb)[idx] = ov;
}

// ---------------- fused post-BN + PReLU + head dot ----------------

__global__ __launch_bounds__(256) void k_final_fused(
    const float* __restrict__ x, const bfu* __restrict__ outf,
    const float* __restrict__ stats, const float* __restrict__ g,
    const float* __restrict__ be, const float* __restrict__ a_ptr,
    const float* __restrict__ Wf, const float* __restrict__ bf_,
    float* __restrict__ z, int Nn, int Nrows) {
    int node = (int)((blockIdx.x * blockDim.x + threadIdx.x) >> 6);
    int lane = threadIdx.x & 63;
    if (node >= Nn) return;
    float a = a_ptr[0];
    float inv = 1.0f / (float)Nrows;
    float s = x[(size_t)node * F_IN + lane] * Wf[lane]
            + x[(size_t)node * F_IN + 64 + lane] * Wf[64 + lane];
    uint2 v  = ((const uint2*)outf)[(size_t)node * 64 + lane];
    float4 wv = ((const float4*)(Wf + F_IN))[lane];
    float4 st1 = ((const float4*)stats)[lane];
    float4 st2 = ((const float4*)(stats + D))[lane];
    float4 gv = ((const float4*)g)[lane];
    float4 bev = ((const float4*)be)[lane];
    float vin[4] = {bf2f(v.x & 0xffffu), bf2f(v.x >> 16),
                    bf2f(v.y & 0xffffu), bf2f(v.y >> 16)};
    float m1[4] = {st1.x, st1.y, st1.z, st1.w};
    float m2[4] = {st2.x, st2.y, st2.z, st2.w};
    float gg[4] = {gv.x, gv.y, gv.z, gv.w};
    float bb[4] = {bev.x, bev.y, bev.z, bev.w};
    float ww[4] = {wv.x, wv.y, wv.z, wv.w};
    #pragma unroll
    for (int t = 0; t < 4; ++t) {
        float m = m1[t] * inv;
        float var = m2[t] * inv - m * m;
        float sc = rsqrtf(var + EPS) * gg[t];
        float sh = bb[t] - m * sc;
        float u = vin[t] * sc + sh;
        u = u >= 0.f ? u : a * u;
        s += u * ww[t];
    }
    #pragma unroll
    for (int off = 32; off; off >>= 1) s += __shfl_down(s, off, 64);
    if (lane == 0) z[node] = s + bf_[0];
}

__global__ __launch_bounds__(256) void k_zstats(const float* __restrict__ z,
                                                float* __restrict__ zs, int n) {
    float s = 0.f, s2 = 0.f;
    for (int i = blockIdx.x * blockDim.x + threadIdx.x; i < n; i += gridDim.x * blockDim.x) {
        float v = z[i];
        s += v; s2 += v * v;
    }
    #pragma unroll
    for (int off = 32; off; off >>= 1) {
        s += __shfl_down(s, off, 64);
        s2 += __shfl_down(s2, off, 64);
    }
    __shared__ float ws[4], ws2[4];
    int lane = threadIdx.x & 63, wid = threadIdx.x >> 6;
    if (lane == 0) { ws[wid] = s; ws2[wid] = s2; }
    __syncthreads();
    if (threadIdx.x == 0) {
        atomicAdd(&zs[0], ws[0] + ws[1] + ws[2] + ws[3]);
        atomicAdd(&zs[1], ws2[0] + ws2[1] + ws2[2] + ws2[3]);
    }
}

__global__ __launch_bounds__(256) void k_logsm(const float* __restrict__ z,
                                               const float* __restrict__ zs,
                                               const float* __restrict__ g,
                                               const float* __restrict__ be,
                                               const float* __restrict__ a_ptr,
                                               float* __restrict__ out, int C, int Ntot) {
    __shared__ float red[4], red2[4];
    int t = threadIdx.x;
    int lane = t & 63, wid = t >> 6;
    float mean = zs[0] / (float)Ntot;
    float var = zs[1] / (float)Ntot - mean * mean;
    float sc = rsqrtf(var + EPS) * g[0];
    float sh = be[0] - mean * sc;
    float a = a_ptr[0];
    const float* zg = z + (size_t)blockIdx.x * C;
    float vals[4];
    int cnt = 0;
    float mx = -3.4e38f;
    for (int i = t; i < C; i += 256) {
        float u = zg[i] * sc + sh;
        u = u >= 0.f ? u : a * u;
        vals[cnt++] = u;
        mx = fmaxf(mx, u);
    }
    #pragma unroll
    for (int off = 32; off; off >>= 1) mx = fmaxf(mx, __shfl_down(mx, off, 64));
    if (lane == 0) red[wid] = mx;
    __syncthreads();
    float M4 = fmaxf(fmaxf(red[0], red[1]), fmaxf(red[2], red[3]));
    float se = 0.f;
    for (int j = 0; j < cnt; ++j) se += expf(vals[j] - M4);
    #pragma unroll
    for (int off = 32; off; off >>= 1) se += __shfl_down(se, off, 64);
    if (lane == 0) red2[wid] = se;
    __syncthreads();
    float S4 = red2[0] + red2[1] + red2[2] + red2[3];
    float lse = logf(S4) + M4;
    cnt = 0;
    for (int i = t; i < C; i += 256) out[(size_t)blockIdx.x * C + i] = vals[cnt++] - lse;
}

// ---------------- launch ----------------

extern "C" void kernel_launch(void* const* d_in, const int* in_sizes, int n_in,
                              void* d_out, int out_size, void* d_ws, size_t ws_size,
                              hipStream_t stream) {
    const float* x      = (const float*)d_in[0];
    const int*   eidx   = (const int*)d_in[1];
    const float* e_w    = (const float*)d_in[2];
    const float* W_pre  = (const float*)d_in[4];
    const float* b_pre  = (const float*)d_in[5];
    const float* g_pre  = (const float*)d_in[6];
    const float* be_pre = (const float*)d_in[7];
    const float* a_pre  = (const float*)d_in[8];
    const float* W_rel  = (const float*)d_in[9];
    const float* b_rel  = (const float*)d_in[10];
    const float* W_root = (const float*)d_in[11];
    const float* g_conv = (const float*)d_in[12];
    const float* be_conv= (const float*)d_in[13];
    const float* a_conv = (const float*)d_in[14];
    const float* W_post = (const float*)d_in[15];
    const float* b_post = (const float*)d_in[16];
    const float* g_post = (const float*)d_in[17];
    const float* be_post= (const float*)d_in[18];
    const float* a_post = (const float*)d_in[19];
    const float* W_fin  = (const float*)d_in[20];
    const float* b_fin  = (const float*)d_in[21];
    const float* g_fin  = (const float*)d_in[22];
    const float* be_fin = (const float*)d_in[23];
    const float* a_fin  = (const float*)d_in[24];

    const int N = in_sizes[0] / F_IN;   // 50000
    const int E = in_sizes[2];          // 800000
    const int L = in_sizes[14];         // 3
    const int Npad = ((N + 511) / 512) * 512;   // rows multiple of 8*BM for XCD swizzle
    const int NRB = Npad / BM;                   // row-blocks (multiple of 8)
    const int NB = (N + 255) >> 8;      // node buckets
    const int* e_src = eidx;
    const int* e_dst = eidx + E;

    uint8_t* wsp = (uint8_t*)d_ws;
    size_t used = 0;
    auto alloc = [&](size_t bytes) -> void* {
        void* p = wsp + used;
        used += (bytes + 255) & ~(size_t)255;
        return p;
    };
    bfu*   xb       = (bfu*)alloc((size_t)Npad * F_IN * 2);
    bfu*   hb0      = (bfu*)alloc((size_t)Npad * D * 2);
    bfu*   hb1      = (bfu*)alloc((size_t)Npad * D * 2);
    bfu*   aggb     = (bfu*)alloc((size_t)Npad * D * 2);
    bfu*   outb     = (bfu*)alloc((size_t)Npad * D * 2);
    bfu*   Wt_pre   = (bfu*)alloc((size_t)D * F_IN * 2);
    bfu*   Wt_rel   = (bfu*)alloc((size_t)L * D * D * 2);
    bfu*   Wt_root  = (bfu*)alloc((size_t)L * D * D * 2);
    bfu*   Wt_post  = (bfu*)alloc((size_t)D * D * 2);
    float* z        = (float*)alloc((size_t)N * 4);
    float* statsall = (float*)alloc((size_t)(5 * 2 * D + 2) * 4);
    int*   bh       = (int*)alloc((size_t)NB * 4);
    int*   bucket_base   = (int*)alloc((size_t)(NB + 1) * 4);
    int*   bucket_cursor = (int*)alloc((size_t)NB * 4);
    int*   row_start= (int*)alloc((size_t)(N + 1) * 4);
    uint2* s_tmp    = (uint2*)alloc((size_t)E * 8);
    uint2* s_edge   = (uint2*)alloc((size_t)E * 8);
    if (used > ws_size) {
        fprintf(stderr, "kernel_launch: ws too small (%zu > %zu)\n", used, ws_size);
        return;
    }
    float* st_pre  = statsall;
    float* st_post = statsall + 4 * 2 * D;
    float* zstats  = statsall + 5 * 2 * D;

    hipMemsetAsync(bh, 0, (size_t)NB * 4, stream);
    hipMemsetAsync(statsall, 0, (size_t)(5 * 2 * D + 2) * 4, stream);

    // front end: cvt + transposes + bucket histogram (one launch)
    const int total4 = N * (F_IN / 4);
    const int CVT_BLOCKS = (total4 + 255) / 256;
    k_front<<<CVT_BLOCKS + 2048 + 512, 256, 0, stream>>>(
        x, e_dst, W_pre, W_rel, W_root, W_post,
        xb, Wt_pre, Wt_rel, Wt_root, Wt_post, bh, CVT_BLOCKS, E, NB, total4);

    // hierarchical counting sort
    k_bscan<<<1, 256, 0, stream>>>(bh, NB, E, bucket_base, bucket_cursor, row_start, N);
    k_binA<<<(E + ACHUNK - 1) / ACHUNK, 256, 0, stream>>>(e_src, e_dst, e_w, E,
                                                          bucket_cursor, s_tmp);
    k_binB<<<NB, 256, 0, stream>>>(s_tmp, bucket_base, s_edge, row_start, N);

    const int gemm_grid = NRB * 4;
    const int bn_blocks = (N * (D / 4) + 255) / 256;
    const int wave_blocks = (N + 3) / 4;

    // preprocess
    gemm_mfma<<<gemm_grid, 256, 0, stream>>>(xb, F_IN, Wt_pre, nullptr, 0, nullptr,
                                             b_pre, outb, st_pre, N, D);
    bn_prelu_bf16<<<bn_blocks, 256, 0, stream>>>(outb, st_pre, g_pre, be_pre, a_pre,
                                                 hb0, N * (D / 4), N);

    bfu* hc = hb0;
    bfu* hn = hb1;
    for (int l = 0; l < L; ++l) {
        float* st = statsall + (1 + l) * 2 * D;
        k_agg<<<wave_blocks, 256, 0, stream>>>(hc, row_start, s_edge, aggb, N);
        gemm_mfma<<<gemm_grid, 256, 0, stream>>>(aggb, D, Wt_rel + (size_t)l * D * D,
                                                 hc, D, Wt_root + (size_t)l * D * D,
                                                 b_rel + (size_t)l * D, outb, st, N, D);
        bn_prelu_bf16<<<bn_blocks, 256, 0, stream>>>(outb, st, g_conv + (size_t)l * D,
                                                     be_conv + (size_t)l * D, a_conv + l,
                                                     hn, N * (D / 4), N);
        bfu* tmp = hc; hc = hn; hn = tmp;
    }

    // postprocess gemm (stats fused) -> fused BN+PReLU+head dot
    gemm_mfma<<<gemm_grid, 256, 0, stream>>>(hc, D, Wt_post, nullptr, 0, nullptr,
                                             b_post, outb, st_post, N, D);
    k_final_fused<<<wave_blocks, 256, 0, stream>>>(x, outb, st_post, g_post, be_post,
                                                   a_post, W_fin, b_fin, z, N, N);
    k_zstats<<<64, 256, 0, stream>>>(z, zstats, N);
    k_logsm<<<N / 1000, 256, 0, stream>>>(z, zstats, g_fin, be_fin, a_fin,
                                          (float*)d_out, 1000, N);
}